// Round 3
// baseline (3105.802 us; speedup 1.0000x reference)
//
#include <hip/hip_runtime.h>

typedef __attribute__((ext_vector_type(8))) short short8;
typedef __attribute__((ext_vector_type(4))) float f32x4;
typedef __attribute__((ext_vector_type(2))) float f32x2;
typedef __attribute__((ext_vector_type(4))) unsigned short us4;
typedef __attribute__((ext_vector_type(2))) unsigned short us2;

#define N_NODES 4096
#define T_STEPS 128
#define H_DIM   64
#define NBLK    256
#define NTHR    512      // 8 waves
#define ROWS    16       // graph rows per block

// workspace layout (bytes) — identical to the proven round-1 layout
#define WS_FLAGS 0u          // 256 flags, 128B apart = 32 KB (heavy init barrier only)
#define WS_WT    32768u      // Wt[256][96] bf16 (combined [Wih;Whh] transposed)
#define WS_WQT   81920u      // Wqt[64][64] bf16
#define WS_SYNC  90112u      // done_flag @ +0, cnt[epoch] @ +128 stride 32B (light barrier)
#define WS_Q0    98304u      // q tiles, 512 KB: tile[node/32] = [hh/16][hh%16][node%32] bf16
#define WS_Q1    622592u
#define WS_NEED  1146880u

// dynamic LDS layout
#define ADJ_STRIDE 4104                  // 4096 + 8 pad
#define ADJ_BYTES  (16u * ADJ_STRIDE * 2u)          // 131328
#define GATE_BYTES 16384u                // [4][16][64] f32
#define S_BYTES    4224u                 // [16][66] f32
#define C_BYTES    4096u                 // [16][64] f32
#define H_BYTES    2304u                 // [16][72] bf16
#define SMEM_SMALL (GATE_BYTES + S_BYTES + C_BYTES + H_BYTES)            // 27008
#define SMEM_BIG   (ADJ_BYTES + SMEM_SMALL)                              // 158336

__device__ __forceinline__ unsigned short f2bf(float f) {   // RNE fp32->bf16
    unsigned x = __float_as_uint(f);
    unsigned r = ((x >> 16) & 1u) + 0x7fffu;
    return (unsigned short)((x + r) >> 16);
}
__device__ __forceinline__ short8 cvt8_trunc_v(f32x4 a, f32x4 b) {  // truncating pack
    union { unsigned u[4]; short8 s; } cv;
    cv.u[0] = __builtin_amdgcn_perm(__float_as_uint(a[1]), __float_as_uint(a[0]), 0x07060302u);
    cv.u[1] = __builtin_amdgcn_perm(__float_as_uint(a[3]), __float_as_uint(a[2]), 0x07060302u);
    cv.u[2] = __builtin_amdgcn_perm(__float_as_uint(b[1]), __float_as_uint(b[0]), 0x07060302u);
    cv.u[3] = __builtin_amdgcn_perm(__float_as_uint(b[3]), __float_as_uint(b[2]), 0x07060302u);
    return cv.s;
}
__device__ __forceinline__ short8 cvt8_trunc(const float* p) {
    return cvt8_trunc_v(*(const f32x4*)p, *(const f32x4*)(p + 4));
}
__device__ __forceinline__ float fast_sigmoid(float x) { return 1.f / (1.f + __expf(-x)); }
__device__ __forceinline__ float fast_tanh(float x)    { return 1.f - 2.f / (1.f + __expf(2.f * x)); }

// ---------------- heavy barrier: init only (publishes plain-stored weights/q0 via wbl2/inv) ----
__device__ __forceinline__ void grid_barrier(int* flags, int bid, int tid, int epoch) {
    __syncthreads();
    if (tid == 0) {
        __builtin_amdgcn_fence(__ATOMIC_RELEASE, "agent");   // wbl2
        __hip_atomic_store(&flags[bid * 32], epoch, __ATOMIC_RELAXED, __HIP_MEMORY_SCOPE_AGENT);
    }
    if (tid < NBLK) {
        int guard = 0;
        while (__hip_atomic_load(&flags[tid * 32], __ATOMIC_RELAXED, __HIP_MEMORY_SCOPE_AGENT) < epoch) {
            __builtin_amdgcn_s_sleep(32);
            if (++guard > (1 << 17)) break;
        }
    }
    __syncthreads();
    if (tid == 0) __builtin_amdgcn_fence(__ATOMIC_ACQUIRE, "agent");  // inv
    __syncthreads();
}

// ---------------- light barrier: per-step. Acquire-only. NO writeback. ----------------
// Producer side: q stores are sc0|sc1 (straight to LLC), drained by vmcnt(0) before arrival.
// Consumer side: after done-flag detection, acquire fence (buffer_inv) drops stale L1/L2 q
// lines; Phase B then uses NORMAL cached loads -> one LLC fill per line per XCD, 31 CUs hit L2.
// (inv + cached-consume proven by the original baseline; sc-store publish proven by round 1.)
__device__ __forceinline__ void light_barrier(int* donef, int* cnt, int tid, int epoch) {
    asm volatile("s_waitcnt vmcnt(0)" ::: "memory");   // drain this wave's q/out/x vmem
    __syncthreads();
    if (tid == 0) {
        int old = __hip_atomic_fetch_add(&cnt[epoch * 8], 1, __ATOMIC_RELAXED, __HIP_MEMORY_SCOPE_AGENT);
        if (old == NBLK - 1)
            __hip_atomic_store(donef, epoch, __ATOMIC_RELAXED, __HIP_MEMORY_SCOPE_AGENT);
    }
    if (tid < 64) {                                    // one wave polls ONE LLC line
        int guard = 0;
        while (__hip_atomic_load(donef, __ATOMIC_RELAXED, __HIP_MEMORY_SCOPE_AGENT) < epoch) {
            __builtin_amdgcn_s_sleep(8);
            if (++guard > (1 << 17)) break;
        }
    }
    __syncthreads();
    if (tid == 0) __builtin_amdgcn_fence(__ATOMIC_ACQUIRE, "agent");  // buffer_inv (acquire half only)
    __syncthreads();
}

#define MFMA16(a, b, c) __builtin_amdgcn_mfma_f32_16x16x32_bf16((a), (b), (c), 0, 0, 0)

// NORMAL cached q load (fills L1+L2): per-XCD L2 takes one LLC fill, other CUs hit L2.
#define QLD(dst, ptr, off) \
    asm volatile("global_load_dwordx4 %0, %1, off offset:" #off \
                 : "=v"(dst) : "v"(ptr))
// one group = 2 k-tiles x 4 nt = 8 loads = 8KB/wave, fully contiguous per instruction.
// ptr is biased +2048 shorts so all 8 offsets fit the signed 13-bit immediate.
#define ISSUE_G(dst, pp) do { \
    QLD((dst)[0], (pp), -4096); QLD((dst)[1], (pp), -3072); \
    QLD((dst)[2], (pp), -2048); QLD((dst)[3], (pp), -1024); \
    QLD((dst)[4], (pp), 0);     QLD((dst)[5], (pp), 1024);  \
    QLD((dst)[6], (pp), 2048);  QLD((dst)[7], (pp), 3072);  \
} while (0)
// counted wait on the asm loads; sched_barrier stops MFMAs hoisting above it (rule #18)
#define WAITV(n) do { asm volatile("s_waitcnt vmcnt(" #n ")" ::: "memory"); \
                      __builtin_amdgcn_sched_barrier(0); } while (0)
#define MFMA_GRP(B) do { \
    acc[0] = MFMA16(a0_, (B)[0], acc[0]); acc[1] = MFMA16(a0_, (B)[1], acc[1]); \
    acc[2] = MFMA16(a0_, (B)[2], acc[2]); acc[3] = MFMA16(a0_, (B)[3], acc[3]); \
    acc[0] = MFMA16(a1_, (B)[4], acc[0]); acc[1] = MFMA16(a1_, (B)[5], acc[1]); \
    acc[2] = MFMA16(a1_, (B)[6], acc[2]); acc[3] = MFMA16(a1_, (B)[7], acc[3]); \
} while (0)

// 256 blocks on 256 CUs (1 block/CU via 158KB LDS) => all resident => flag barrier safe.
// ws poisoned 0xAA => flags/done start negative; epochs count 1,2,...
template <bool ADJL>
__global__ __launch_bounds__(NTHR, 1) void glstm_kernel(
    const float* __restrict__ x,      // [4096][128][32]
    const float* __restrict__ adj,    // [4096][4096]
    const float* __restrict__ w_ih,   // [32][256]
    const float* __restrict__ w_hh,   // [64][256]
    const float* __restrict__ bias,   // [256]
    const float* __restrict__ w_q,    // [64][64]
    const float* __restrict__ bias_q, // [64]
    float* __restrict__ out,          // [4096][128][64]
    unsigned char* __restrict__ ws)
{
    const int tid  = threadIdx.x;
    const int bid  = blockIdx.x;
    const int wave = tid >> 6;
    const int lane = tid & 63;
    const int l15  = lane & 15;
    const int quad = lane >> 4;
    const int rowbase = bid * ROWS;

    int* flags = (int*)(ws + WS_FLAGS);
    int* donef = (int*)(ws + WS_SYNC);
    int* cnt   = (int*)(ws + WS_SYNC + 128);
    unsigned short* Wt  = (unsigned short*)(ws + WS_WT);
    unsigned short* Wqt = (unsigned short*)(ws + WS_WQT);
    unsigned short* qb0 = (unsigned short*)(ws + WS_Q0);
    unsigned short* qb1 = (unsigned short*)(ws + WS_Q1);

    extern __shared__ unsigned char smem[];
    unsigned short* adj_lds = (unsigned short*)smem;                 // [16][4104] (ADJL only)
    const unsigned off = ADJL ? ADJ_BYTES : 0u;
    float* gate_lds = (float*)(smem + off);                          // [4][16][64]
    float* s_lds    = (float*)(smem + off + GATE_BYTES);             // [16][66]
    float* c_lds    = (float*)(smem + off + GATE_BYTES + S_BYTES);   // [16][64]
    unsigned short* h_lds = (unsigned short*)(smem + off + GATE_BYTES + S_BYTES + C_BYTES); // [16][72]

    // ---------------- init: weights, q0 (tile layout), zero state, cnt zeroing, adj->LDS ------
    if (tid < 96) {
        float v = (tid < 32) ? w_ih[tid * 256 + bid] : w_hh[(tid - 32) * 256 + bid];
        Wt[bid * 96 + tid] = f2bf(v);
    }
    if (bid < 64 && tid < 64) Wqt[bid * 64 + tid] = f2bf(w_q[tid * 64 + bid]);
    if (tid == 0 && bid < T_STEPS + 2) cnt[bid * 8] = 0;     // epochs 0..129 (plain store, published below)
    for (int idx = tid; idx < ROWS * 64; idx += NTHR) {      // q0 = tanh(bq), fragment-tile layout
        int r = idx >> 6, hh = idx & 63;
        qb0[((size_t)(bid >> 1) * 4 + (hh >> 4)) * 512 + (hh & 15) * 32 + (bid & 1) * 16 + r]
            = f2bf(fast_tanh(bias_q[hh]));
    }
    for (int idx = tid; idx < ROWS * 64; idx += NTHR) {
        int r = idx >> 6, cc = idx & 63;
        c_lds[r * 64 + cc] = 0.f;
        s_lds[r * 66 + cc] = 0.f;
        h_lds[r * 72 + cc] = 0;
    }
    if (ADJL) {
        for (int idx = tid; idx < ROWS * N_NODES; idx += NTHR) {
            int r = idx >> 12, c = idx & (N_NODES - 1);
            adj_lds[r * ADJ_STRIDE + c] = f2bf(adj[(size_t)(rowbase + r) * N_NODES + c]);
        }
    }
    grid_barrier(flags, bid, tid, 1);        // ONLY heavy barrier: publishes Wt/Wqt/qb0/cnt

    // ---------------- hoist weight fragments into registers ----------------
    const int g    = wave >> 1;        // gate 0..3
    const int half = wave & 1;
    const int nc0  = g * 64 + half * 32 + l15;
    short8 wA[2][3];
#pragma unroll
    for (int nt = 0; nt < 2; ++nt)
#pragma unroll
        for (int kk = 0; kk < 3; ++kk)
            wA[nt][kk] = *(const short8*)(Wt + (nc0 + nt * 16) * 96 + kk * 32 + quad * 8);
    const float bv0 = bias[nc0], bv1 = bias[nc0 + 16];
    const int hhq = (wave & 3) * 16 + l15;
    short8 wQ[2];
#pragma unroll
    for (int kk = 0; kk < 2; ++kk)
        wQ[kk] = *(const short8*)(Wqt + hhq * 64 + kk * 32 + quad * 8);
    const float bqv = bias_q[hhq];

    const float* xlane   = x + (size_t)(rowbase + l15) * T_STEPS * 32 + quad * 8;
    const float* adjlane = adj + (size_t)(rowbase + l15) * N_NODES + wave * 512 + quad * 8;
    const unsigned short* albase = adj_lds + l15 * ADJ_STRIDE + wave * 512 + quad * 8;
    // q store address (fragment-tile layout), waves 0..3
    unsigned short* const qdoff = (unsigned short*)(((size_t)(bid >> 1) * 4 + (wave & 3)) * 512
                                   + l15 * 32 + (bid & 1) * 16 + quad * 4);

    f32x4 xa = *(const f32x4*)(xlane);          // x_0 fragment
    f32x4 xb = *(const f32x4*)(xlane + 4);

    // ---------------- Phase A: gates = [x_t | h] @ W + b (block-local; runs pre-barrier) -----
    auto phaseA = [&]() {
        f32x4 acc0 = {0.f, 0.f, 0.f, 0.f};
        f32x4 acc1 = {0.f, 0.f, 0.f, 0.f};
        short8 a0 = cvt8_trunc_v(xa, xb);
        acc0 = MFMA16(a0, wA[0][0], acc0);
        acc1 = MFMA16(a0, wA[1][0], acc1);
#pragma unroll
        for (int kk = 1; kk < 3; ++kk) {
            short8 a = *(const short8*)(h_lds + l15 * 72 + (kk - 1) * 32 + quad * 8);
            acc0 = MFMA16(a, wA[0][kk], acc0);
            acc1 = MFMA16(a, wA[1][kk], acc1);
        }
#pragma unroll
        for (int nt = 0; nt < 2; ++nt) {
            f32x4 acc = nt ? acc1 : acc0;
            float bv  = nt ? bv1 : bv0;
            int colg  = half * 32 + nt * 16 + l15;
#pragma unroll
            for (int r = 0; r < 4; ++r) {
                float v = acc[r] + bv;
                v = (g == 2) ? fast_tanh(v) : fast_sigmoid(v);
                gate_lds[(g * 16 + quad * 4 + r) * 64 + colg] = v;
            }
        }
    };

    phaseA();                                   // gates for t=0 (h=0)
    xa = *(const f32x4*)(xlane + 32);           // prefetch x_1
    xb = *(const f32x4*)(xlane + 36);

    for (int t = 0; t < T_STEPS; ++t) {
        const unsigned short* qcur = (t & 1) ? qb1 : qb0;
        unsigned short*       qnxt = (t & 1) ? qb0 : qb1;

        // ---------------- Phase B: s += adj[rows,:] @ q_t  (cached q loads, 2-buf pipeline) ---
        {
            f32x4 acc[4];
#pragma unroll
            for (int nt = 0; nt < 4; ++nt) acc[nt] = (f32x4){0.f, 0.f, 0.f, 0.f};
            // biased base: wave's 16 k-tiles start + per-lane fragment offset + 2048 shorts
            const unsigned short* qp = qcur + ((size_t)wave << 15) + (l15 << 5) + (quad << 3) + 2048;
            short8 qv2[2][8];
            short8 a0_, a1_;
            if constexpr (ADJL) {
                a0_ = *(const short8*)(albase);
                a1_ = *(const short8*)(albase + 32);
            }
            ISSUE_G(qv2[0], qp);
#pragma unroll
            for (int gg = 0; gg < 8; ++gg) {
                if (gg < 7) { const unsigned short* pg = qp + (gg + 1) * 4096; ISSUE_G(qv2[(gg + 1) & 1], pg); }
                if constexpr (ADJL) {
                    short8 na0, na1;
                    if (gg < 7) {
                        na0 = *(const short8*)(albase + (2 * gg + 2) * 32);
                        na1 = *(const short8*)(albase + (2 * gg + 3) * 32);
                        WAITV(8);
                    } else {
                        WAITV(0);
                    }
                    MFMA_GRP(qv2[gg & 1]);
                    if (gg < 7) { a0_ = na0; a1_ = na1; }
                } else {
                    a0_ = cvt8_trunc(adjlane + (2 * gg) * 32);
                    a1_ = cvt8_trunc(adjlane + (2 * gg + 1) * 32);
                    WAITV(0);                      // mixed compiler loads: conservative
                    MFMA_GRP(qv2[gg & 1]);
                }
            }
#pragma unroll
            for (int nt = 0; nt < 4; ++nt)
#pragma unroll
                for (int r = 0; r < 4; ++r)
                    atomicAdd(&s_lds[(quad * 4 + r) * 66 + nt * 16 + l15], acc[nt][r]);
        }
        __syncthreads();

        // ---------------- Phase C: state update + h output (fp32), reset s ----------------
        {
            const int r  = tid >> 5;
            const int c0 = (tid & 31) * 2;
            float hn[2];
#pragma unroll
            for (int j = 0; j < 2; ++j) {
                int cc = c0 + j;
                float s = s_lds[r * 66 + cc];
                s_lds[r * 66 + cc] = 0.f;
                float iv = gate_lds[(0 * 16 + r) * 64 + cc];
                float fv = gate_lds[(1 * 16 + r) * 64 + cc];
                float gv = gate_lds[(2 * 16 + r) * 64 + cc];
                float ov = gate_lds[(3 * 16 + r) * 64 + cc];
                float cn = fv * (c_lds[r * 64 + cc] + s) + iv * gv;
                hn[j] = ov * fast_tanh(cn);
                c_lds[r * 64 + cc] = cn;
            }
            us2 hv; hv[0] = f2bf(hn[0]); hv[1] = f2bf(hn[1]);
            *(us2*)(h_lds + r * 72 + c0) = hv;
            *(f32x2*)(out + ((size_t)(rowbase + r) * T_STEPS + t) * H_DIM + c0) = (f32x2){hn[0], hn[1]};
        }
        __syncthreads();

        if (t < T_STEPS - 1) {
            // ------------ Phase D: q_{t+1} = tanh(h @ Wq + bq), sc1 store in tile layout -----
            if (wave < 4) {
                f32x4 acc = {0.f, 0.f, 0.f, 0.f};
#pragma unroll
                for (int kk = 0; kk < 2; ++kk) {
                    short8 a = *(const short8*)(h_lds + l15 * 72 + kk * 32 + quad * 8);
                    acc = MFMA16(a, wQ[kk], acc);
                }
                us4 qv;
#pragma unroll
                for (int r = 0; r < 4; ++r) qv[r] = f2bf(fast_tanh(acc[r] + bqv));
                unsigned short* qdst = qnxt + (size_t)qdoff;
                asm volatile("global_store_dwordx2 %0, %1, off sc0 sc1" :: "v"(qdst), "v"(qv) : "memory");
            }
            phaseA();                                        // gates for t+1 (off critical path)
            if (t < T_STEPS - 2) {
                xa = *(const f32x4*)(xlane + (t + 2) * 32);  // prefetch x_{t+2}
                xb = *(const f32x4*)(xlane + (t + 2) * 32 + 4);
            }
            light_barrier(donef, cnt, tid, t + 2);
        }
    }
}

extern "C" void kernel_launch(void* const* d_in, const int* in_sizes, int n_in,
                              void* d_out, int out_size, void* d_ws, size_t ws_size,
                              hipStream_t stream) {
    if (ws_size < WS_NEED) return;
    const float* x      = (const float*)d_in[0];
    const float* adj    = (const float*)d_in[1];
    const float* w_ih   = (const float*)d_in[2];
    const float* w_hh   = (const float*)d_in[3];
    const float* bias   = (const float*)d_in[4];
    const float* w_q    = (const float*)d_in[5];
    const float* bias_q = (const float*)d_in[6];
    float* o = (float*)d_out;
    unsigned char* w = (unsigned char*)d_ws;

    hipError_t e = hipFuncSetAttribute((const void*)glstm_kernel<true>,
                                       hipFuncAttributeMaxDynamicSharedMemorySize, SMEM_BIG);
    if (e == hipSuccess) {
        glstm_kernel<true><<<NBLK, NTHR, SMEM_BIG, stream>>>(x, adj, w_ih, w_hh, bias, w_q, bias_q, o, w);
    } else {
        glstm_kernel<false><<<NBLK, NTHR, SMEM_SMALL, stream>>>(x, adj, w_ih, w_hh, bias, w_q, bias_q, o, w);
    }
}

// Round 4
// 2598.662 us; speedup vs baseline: 1.1952x; 1.1952x over previous
//
#include <hip/hip_runtime.h>

typedef __attribute__((ext_vector_type(8))) short short8;
typedef __attribute__((ext_vector_type(4))) float f32x4;
typedef __attribute__((ext_vector_type(2))) float f32x2;
typedef __attribute__((ext_vector_type(2))) unsigned short us2;

#define N_NODES 4096
#define T_STEPS 128
#define H_DIM   64
#define NBLK    256
#define NTHR    512      // 8 waves
#define ROWS    16       // graph rows per block

// workspace layout (bytes) — same envelope as the proven round-1 layout (WS_NEED unchanged)
#define WS_FLAGS 0u          // 256 flags, 128B apart = 32 KB (heavy init barrier only)
#define WS_WT    32768u      // Wt[256][96] bf16 (combined [Wih;Whh] transposed)
#define WS_WQT   81920u      // Wqt[64][64] bf16
#define WS_SYNC  90112u      // 8 cumulative arrival counters, 128B apart (light barrier)
#define WS_Q0    98304u      // q fp8 tiles, 256 KB: tile[node/32] = [hh/16][hh%16][node%32] bytes
#define WS_Q1    360448u
#define WS_NEED  1146880u

// dynamic LDS layout (adj now fp8: 16 rows x (4096 + 16 pad) bytes)
#define ADJ_STRIDE_B 4112u
#define ADJ_BYTES  (16u * ADJ_STRIDE_B)             // 65792
#define GATE_BYTES 16384u                // [4][16][64] f32
#define S_BYTES    4224u                 // [16][66] f32
#define C_BYTES    4096u                 // [16][64] f32
#define H_BYTES    2304u                 // [16][72] bf16
#define SMEM_TOT   (ADJ_BYTES + GATE_BYTES + S_BYTES + C_BYTES + H_BYTES)   // 92800

__device__ __forceinline__ unsigned short f2bf(float f) {   // RNE fp32->bf16
    unsigned x = __float_as_uint(f);
    unsigned r = ((x >> 16) & 1u) + 0x7fffu;
    return (unsigned short)((x + r) >> 16);
}
__device__ __forceinline__ short8 cvt8_trunc_v(f32x4 a, f32x4 b) {  // truncating pack f32->bf16 x8
    union { unsigned u[4]; short8 s; } cv;
    cv.u[0] = __builtin_amdgcn_perm(__float_as_uint(a[1]), __float_as_uint(a[0]), 0x07060302u);
    cv.u[1] = __builtin_amdgcn_perm(__float_as_uint(a[3]), __float_as_uint(a[2]), 0x07060302u);
    cv.u[2] = __builtin_amdgcn_perm(__float_as_uint(b[1]), __float_as_uint(b[0]), 0x07060302u);
    cv.u[3] = __builtin_amdgcn_perm(__float_as_uint(b[3]), __float_as_uint(b[2]), 0x07060302u);
    return cv.s;
}
__device__ __forceinline__ float fast_sigmoid(float x) { return 1.f / (1.f + __expf(-x)); }
__device__ __forceinline__ float fast_tanh(float x)    { return 1.f - 2.f / (1.f + __expf(2.f * x)); }

// ---------------- heavy barrier: init only (publishes plain-stored weights/q0 via wbl2/inv) ----
__device__ __forceinline__ void grid_barrier(int* flags, int bid, int tid, int epoch) {
    __syncthreads();
    if (tid == 0) {
        __builtin_amdgcn_fence(__ATOMIC_RELEASE, "agent");   // wbl2
        __hip_atomic_store(&flags[bid * 32], epoch, __ATOMIC_RELAXED, __HIP_MEMORY_SCOPE_AGENT);
    }
    if (tid < NBLK) {
        int guard = 0;
        while (__hip_atomic_load(&flags[tid * 32], __ATOMIC_RELAXED, __HIP_MEMORY_SCOPE_AGENT) < epoch) {
            __builtin_amdgcn_s_sleep(32);
            if (++guard > (1 << 17)) break;
        }
    }
    __syncthreads();
    if (tid == 0) __builtin_amdgcn_fence(__ATOMIC_ACQUIRE, "agent");  // inv
    __syncthreads();
}

// ---------------- light barrier: per-step. NO cache fences (round-1 proven semantics). -----
// Cumulative distributed arrival: block bid adds 1 to cnt[bid&7] each step; sum over the 8
// lines >= 256*k  =>  every block has arrived >= k times (each block adds exactly 1/step and
// cannot pass barrier k-1 early — monotone induction). No per-epoch reset, no staleness.
// q coherence: sc0|sc1 stores (LLC), drained by vmcnt(0) BEFORE arrival; sc0|sc1 loads (LLC).
__device__ __forceinline__ void light_barrier(int* cnt, int bid, int tid, int arrivals) {
    asm volatile("s_waitcnt vmcnt(0)" ::: "memory");   // drain this wave's q/out/x vmem
    __syncthreads();
    if (tid == 0)
        __hip_atomic_fetch_add(&cnt[(bid & 7) * 32], 1, __ATOMIC_RELAXED, __HIP_MEMORY_SCOPE_AGENT);
    if (tid < 64) {                                    // one wave gathers 8 lines + shfl-reduce
        const int target = arrivals * NBLK;
        int guard = 0;
        for (;;) {
            int v = (tid < 8)
                ? __hip_atomic_load(&cnt[tid * 32], __ATOMIC_RELAXED, __HIP_MEMORY_SCOPE_AGENT) : 0;
            v += __shfl_xor(v, 4);
            v += __shfl_xor(v, 2);
            v += __shfl_xor(v, 1);
            if (__builtin_amdgcn_readfirstlane(v) >= target) break;
            __builtin_amdgcn_s_sleep(8);
            if (++guard > (1 << 17)) break;
        }
    }
    __syncthreads();
}

#define MFMA16(a, b, c)  __builtin_amdgcn_mfma_f32_16x16x32_bf16((a), (b), (c), 0, 0, 0)
#define MFMAF8(a, b, c)  __builtin_amdgcn_mfma_f32_16x16x32_fp8_fp8((a), (b), (c), 0, 0, 0)

// LLC-coherent q load: 8B fp8 fragment, bypass L1/L2 (sc0 sc1). offset is a literal.
#define QLD(dst, ptr, off) \
    asm volatile("global_load_dwordx2 %0, %1, off offset:" #off " sc0 sc1" \
                 : "=v"(dst) : "v"(ptr))
// one group = 2 node-tiles x 4 h-tiles = 8 fragment loads; each load covers 512B contiguous.
#define ISSUE_G(dst, pp) do { \
    QLD((dst)[0], (pp), 0);    QLD((dst)[1], (pp), 512);  \
    QLD((dst)[2], (pp), 1024); QLD((dst)[3], (pp), 1536); \
    QLD((dst)[4], (pp), 2048); QLD((dst)[5], (pp), 2560); \
    QLD((dst)[6], (pp), 3072); QLD((dst)[7], (pp), 3584); \
} while (0)
// counted wait on the asm loads; sched_barrier stops MFMAs hoisting above it (rule #18)
#define WAITV(n) do { asm volatile("s_waitcnt vmcnt(" #n ")" ::: "memory"); \
                      __builtin_amdgcn_sched_barrier(0); } while (0)
#define MFMA_GRP(B) do { \
    acc[0] = MFMAF8(a0_, (B)[0], acc[0]); acc[1] = MFMAF8(a0_, (B)[1], acc[1]); \
    acc[2] = MFMAF8(a0_, (B)[2], acc[2]); acc[3] = MFMAF8(a0_, (B)[3], acc[3]); \
    acc[0] = MFMAF8(a1_, (B)[4], acc[0]); acc[1] = MFMAF8(a1_, (B)[5], acc[1]); \
    acc[2] = MFMAF8(a1_, (B)[6], acc[2]); acc[3] = MFMAF8(a1_, (B)[7], acc[3]); \
} while (0)

// 256 blocks on 256 CUs (1 block/CU via 93KB LDS) => all resident => flag barrier safe.
// ws poisoned 0xAA => flags start negative; cnt zeroed by block 0 pre-heavy-barrier.
__global__ __launch_bounds__(NTHR, 1) void glstm_kernel(
    const float* __restrict__ x,      // [4096][128][32]
    const float* __restrict__ adj,    // [4096][4096]
    const float* __restrict__ w_ih,   // [32][256]
    const float* __restrict__ w_hh,   // [64][256]
    const float* __restrict__ bias,   // [256]
    const float* __restrict__ w_q,    // [64][64]
    const float* __restrict__ bias_q, // [64]
    float* __restrict__ out,          // [4096][128][64]
    unsigned char* __restrict__ ws)
{
    const int tid  = threadIdx.x;
    const int bid  = blockIdx.x;
    const int wave = tid >> 6;
    const int lane = tid & 63;
    const int l15  = lane & 15;
    const int quad = lane >> 4;
    const int rowbase = bid * ROWS;

    int* flags = (int*)(ws + WS_FLAGS);
    int* cnt   = (int*)(ws + WS_SYNC);
    unsigned short* Wt  = (unsigned short*)(ws + WS_WT);
    unsigned short* Wqt = (unsigned short*)(ws + WS_WQT);
    unsigned char* qb0 = ws + WS_Q0;
    unsigned char* qb1 = ws + WS_Q1;

    extern __shared__ unsigned char smem[];
    unsigned char* adj_lds = smem;                                   // [16][4112] fp8 (x4096 scale)
    float* gate_lds = (float*)(smem + ADJ_BYTES);                    // [4][16][64]
    float* s_lds    = (float*)(smem + ADJ_BYTES + GATE_BYTES);       // [16][66]
    float* c_lds    = (float*)(smem + ADJ_BYTES + GATE_BYTES + S_BYTES);   // [16][64]
    unsigned short* h_lds = (unsigned short*)(smem + ADJ_BYTES + GATE_BYTES + S_BYTES + C_BYTES); // [16][72]

    // ---------------- init: weights, q0 (fp8 tiles), zero state/counters, adj->LDS fp8 ------
    if (tid < 96) {
        float v = (tid < 32) ? w_ih[tid * 256 + bid] : w_hh[(tid - 32) * 256 + bid];
        Wt[bid * 96 + tid] = f2bf(v);
    }
    if (bid < 64 && tid < 64) Wqt[bid * 64 + tid] = f2bf(w_q[tid * 64 + bid]);
    if (bid == 0 && tid < 8) cnt[tid * 32] = 0;              // cumulative counters start at 0
    for (int idx = tid; idx < ROWS * 64; idx += NTHR) {      // q0 = tanh(bq), fp8 fragment tiles
        int r = idx >> 6, hh = idx & 63;
        float v = fast_tanh(bias_q[hh]);
        qb0[(size_t)(bid >> 1) * 2048 + (hh >> 4) * 512 + (hh & 15) * 32 + (bid & 1) * 16 + r]
            = (unsigned char)(__builtin_amdgcn_cvt_pk_fp8_f32(v, v, 0, false) & 0xFF);
    }
    for (int idx = tid; idx < ROWS * 64; idx += NTHR) {
        int r = idx >> 6, cc = idx & 63;
        c_lds[r * 64 + cc] = 0.f;
        s_lds[r * 66 + cc] = 0.f;
        h_lds[r * 72 + cc] = 0;
    }
    // adj -> LDS as fp8 e4m3, pre-scaled by 2^12 so [0,1/4096) maps into e4m3 range
    for (int idx = tid; idx < ROWS * (N_NODES / 2); idx += NTHR) {
        int r = idx >> 11, c2 = idx & (N_NODES / 2 - 1);
        f32x2 av = *(const f32x2*)(adj + (size_t)(rowbase + r) * N_NODES + c2 * 2);
        int pk = __builtin_amdgcn_cvt_pk_fp8_f32(av[0] * 4096.f, av[1] * 4096.f, 0, false);
        *(unsigned short*)(adj_lds + r * ADJ_STRIDE_B + c2 * 2) = (unsigned short)pk;
    }
    grid_barrier(flags, bid, tid, 1);        // ONLY heavy barrier: publishes Wt/Wqt/qb0/cnt

    // ---------------- hoist weight fragments into registers ----------------
    const int g    = wave >> 1;        // gate 0..3
    const int half = wave & 1;
    const int nc0  = g * 64 + half * 32 + l15;
    short8 wA[2][3];
#pragma unroll
    for (int nt = 0; nt < 2; ++nt)
#pragma unroll
        for (int kk = 0; kk < 3; ++kk)
            wA[nt][kk] = *(const short8*)(Wt + (nc0 + nt * 16) * 96 + kk * 32 + quad * 8);
    const float bv0 = bias[nc0], bv1 = bias[nc0 + 16];
    const int hhq = (wave & 3) * 16 + l15;
    short8 wQ[2];
#pragma unroll
    for (int kk = 0; kk < 2; ++kk)
        wQ[kk] = *(const short8*)(Wqt + hhq * 64 + kk * 32 + quad * 8);
    const float bqv = bias_q[hhq];

    const float* xlane = x + (size_t)(rowbase + l15) * T_STEPS * 32 + quad * 8;
    const unsigned char* albase = adj_lds + l15 * ADJ_STRIDE_B + wave * 512 + quad * 8;
    // q store byte offset (fp8 fragment-tile layout), waves 0..3
    const size_t qdoff = (size_t)(bid >> 1) * 2048 + (size_t)(wave & 3) * 512
                       + l15 * 32 + (bid & 1) * 16 + quad * 4;

    f32x4 xa = *(const f32x4*)(xlane);          // x_0 fragment
    f32x4 xb = *(const f32x4*)(xlane + 4);

    // ---------------- Phase A: gates = [x_t | h] @ W + b (block-local, bf16 MFMA) ----------
    auto phaseA = [&]() {
        f32x4 acc0 = {0.f, 0.f, 0.f, 0.f};
        f32x4 acc1 = {0.f, 0.f, 0.f, 0.f};
        short8 a0 = cvt8_trunc_v(xa, xb);
        acc0 = MFMA16(a0, wA[0][0], acc0);
        acc1 = MFMA16(a0, wA[1][0], acc1);
#pragma unroll
        for (int kk = 1; kk < 3; ++kk) {
            short8 a = *(const short8*)(h_lds + l15 * 72 + (kk - 1) * 32 + quad * 8);
            acc0 = MFMA16(a, wA[0][kk], acc0);
            acc1 = MFMA16(a, wA[1][kk], acc1);
        }
#pragma unroll
        for (int nt = 0; nt < 2; ++nt) {
            f32x4 acc = nt ? acc1 : acc0;
            float bv  = nt ? bv1 : bv0;
            int colg  = half * 32 + nt * 16 + l15;
#pragma unroll
            for (int r = 0; r < 4; ++r) {
                float v = acc[r] + bv;
                v = (g == 2) ? fast_tanh(v) : fast_sigmoid(v);
                gate_lds[(g * 16 + quad * 4 + r) * 64 + colg] = v;
            }
        }
    };

    phaseA();                                   // gates for t=0 (h=0)
    xa = *(const f32x4*)(xlane + 32);           // prefetch x_1
    xb = *(const f32x4*)(xlane + 36);

    for (int t = 0; t < T_STEPS; ++t) {
        const unsigned char* qcur = (t & 1) ? qb1 : qb0;
        unsigned char*       qnxt = (t & 1) ? qb0 : qb1;

        // ------------ Phase B: s += adj[rows,:] @ q_t  (fp8 MFMA, sc-bypass loads) ----------
        {
            f32x4 acc[4];
#pragma unroll
            for (int nt = 0; nt < 4; ++nt) acc[nt] = (f32x4){0.f, 0.f, 0.f, 0.f};
            // wave owns 16 node-tiles: tiles [wave*16, wave*16+16)
            const unsigned char* qp = qcur + (size_t)(wave * 16) * 2048 + (l15 << 5) + (quad << 3);
            long qv2[2][8];
            long a0_ = *(const long*)(albase);
            long a1_ = *(const long*)(albase + 32);
            ISSUE_G(qv2[0], qp);
#pragma unroll
            for (int gg = 0; gg < 8; ++gg) {
                if (gg < 7) { const unsigned char* pg = qp + (gg + 1) * 4096; ISSUE_G(qv2[(gg + 1) & 1], pg); }
                long na0, na1;
                if (gg < 7) {
                    na0 = *(const long*)(albase + (gg + 1) * 64);
                    na1 = *(const long*)(albase + (gg + 1) * 64 + 32);
                    WAITV(8);
                } else {
                    WAITV(0);
                }
                MFMA_GRP(qv2[gg & 1]);
                if (gg < 7) { a0_ = na0; a1_ = na1; }
            }
            // rescale (adj was x4096 in fp8) and reduce across waves
#pragma unroll
            for (int nt = 0; nt < 4; ++nt)
#pragma unroll
                for (int r = 0; r < 4; ++r)
                    atomicAdd(&s_lds[(quad * 4 + r) * 66 + nt * 16 + l15],
                              acc[nt][r] * (1.0f / 4096.0f));
        }
        __syncthreads();

        // ---------------- Phase C: state update + h output (fp32), reset s ----------------
        {
            const int r  = tid >> 5;
            const int c0 = (tid & 31) * 2;
            float hn[2];
#pragma unroll
            for (int j = 0; j < 2; ++j) {
                int cc = c0 + j;
                float s = s_lds[r * 66 + cc];
                s_lds[r * 66 + cc] = 0.f;
                float iv = gate_lds[(0 * 16 + r) * 64 + cc];
                float fv = gate_lds[(1 * 16 + r) * 64 + cc];
                float gv = gate_lds[(2 * 16 + r) * 64 + cc];
                float ov = gate_lds[(3 * 16 + r) * 64 + cc];
                float cn = fv * (c_lds[r * 64 + cc] + s) + iv * gv;
                hn[j] = ov * fast_tanh(cn);
                c_lds[r * 64 + cc] = cn;
            }
            us2 hv; hv[0] = f2bf(hn[0]); hv[1] = f2bf(hn[1]);
            *(us2*)(h_lds + r * 72 + c0) = hv;
            *(f32x2*)(out + ((size_t)(rowbase + r) * T_STEPS + t) * H_DIM + c0) = (f32x2){hn[0], hn[1]};
        }
        __syncthreads();

        if (t < T_STEPS - 1) {
            // -------- Phase D: q_{t+1} = tanh(h @ Wq + bq) -> fp8, sc1 store (tile layout) ---
            if (wave < 4) {
                f32x4 acc = {0.f, 0.f, 0.f, 0.f};
#pragma unroll
                for (int kk = 0; kk < 2; ++kk) {
                    short8 a = *(const short8*)(h_lds + l15 * 72 + kk * 32 + quad * 8);
                    acc = MFMA16(a, wQ[kk], acc);
                }
                float q0 = fast_tanh(acc[0] + bqv), q1 = fast_tanh(acc[1] + bqv);
                float q2 = fast_tanh(acc[2] + bqv), q3 = fast_tanh(acc[3] + bqv);
                int pk = __builtin_amdgcn_cvt_pk_fp8_f32(q0, q1, 0, false);
                pk     = __builtin_amdgcn_cvt_pk_fp8_f32(q2, q3, pk, true);
                unsigned char* qdst = qnxt + qdoff;
                asm volatile("global_store_dword %0, %1, off sc0 sc1" :: "v"(qdst), "v"(pk) : "memory");
            }
            phaseA();                                        // gates for t+1 (off critical path)
            if (t < T_STEPS - 2) {
                xa = *(const f32x4*)(xlane + (t + 2) * 32);  // prefetch x_{t+2}
                xb = *(const f32x4*)(xlane + (t + 2) * 32 + 4);
            }
            light_barrier(cnt, bid, tid, t + 1);
        }
    }
}

extern "C" void kernel_launch(void* const* d_in, const int* in_sizes, int n_in,
                              void* d_out, int out_size, void* d_ws, size_t ws_size,
                              hipStream_t stream) {
    if (ws_size < WS_NEED) return;
    const float* x      = (const float*)d_in[0];
    const float* adj    = (const float*)d_in[1];
    const float* w_ih   = (const float*)d_in[2];
    const float* w_hh   = (const float*)d_in[3];
    const float* bias   = (const float*)d_in[4];
    const float* w_q    = (const float*)d_in[5];
    const float* bias_q = (const float*)d_in[6];
    float* o = (float*)d_out;
    unsigned char* w = (unsigned char*)d_ws;

    hipFuncSetAttribute((const void*)glstm_kernel,
                        hipFuncAttributeMaxDynamicSharedMemorySize, SMEM_TOT);
    glstm_kernel<<<NBLK, NTHR, SMEM_TOT, stream>>>(x, adj, w_ih, w_hh, bias, w_q, bias_q, o, w);
}

// Round 5
// 2546.133 us; speedup vs baseline: 1.2198x; 1.0206x over previous
//
#include <hip/hip_runtime.h>

typedef __attribute__((ext_vector_type(8))) short short8;
typedef __attribute__((ext_vector_type(4))) float f32x4;
typedef __attribute__((ext_vector_type(2))) float f32x2;
typedef __attribute__((ext_vector_type(2))) unsigned short us2;
typedef __attribute__((ext_vector_type(2))) long lx2;     // 16B (avoid HIP's long2)

#define N_NODES 4096
#define T_STEPS 128
#define H_DIM   64
#define NBLK    256
#define NTHR    512      // 8 waves
#define ROWS    16       // graph rows per block

// workspace layout (bytes) — same envelope as the proven round-1/4 layout
#define WS_FLAGS 0u          // 256 flags, 128B apart = 32 KB (heavy init barrier only)
#define WS_WT    32768u      // Wt[256][96] bf16 (combined [Wih;Whh] transposed)
#define WS_WQT   81920u      // Wqt[64][64] bf16
#define WS_SYNC  90112u      // 8 cumulative arrival counters, 128B apart (light barrier)
#define WS_Q0    98304u      // q fp8 supertiles, 256 KB (layout: see Phase B/D)
#define WS_Q1    360448u
#define WS_NEED  1146880u

// dynamic LDS layout (adj fp8: 16 rows x (4096 + 16 pad) bytes)
#define ADJ_STRIDE_B 4112u
#define ADJ_BYTES  (16u * ADJ_STRIDE_B)             // 65792
#define GATE_BYTES 16384u                // [4][16][64] f32
#define S_BYTES    4224u                 // [16][66] f32
#define C_BYTES    4096u                 // [16][64] f32
#define H_BYTES    2304u                 // [16][72] bf16
#define SMEM_TOT   (ADJ_BYTES + GATE_BYTES + S_BYTES + C_BYTES + H_BYTES)   // 92800

__device__ __forceinline__ unsigned short f2bf(float f) {   // RNE fp32->bf16
    unsigned x = __float_as_uint(f);
    unsigned r = ((x >> 16) & 1u) + 0x7fffu;
    return (unsigned short)((x + r) >> 16);
}
__device__ __forceinline__ short8 cvt8_trunc_v(f32x4 a, f32x4 b) {  // truncating pack f32->bf16 x8
    union { unsigned u[4]; short8 s; } cv;
    cv.u[0] = __builtin_amdgcn_perm(__float_as_uint(a[1]), __float_as_uint(a[0]), 0x07060302u);
    cv.u[1] = __builtin_amdgcn_perm(__float_as_uint(a[3]), __float_as_uint(a[2]), 0x07060302u);
    cv.u[2] = __builtin_amdgcn_perm(__float_as_uint(b[1]), __float_as_uint(b[0]), 0x07060302u);
    cv.u[3] = __builtin_amdgcn_perm(__float_as_uint(b[3]), __float_as_uint(b[2]), 0x07060302u);
    return cv.s;
}
__device__ __forceinline__ float fast_sigmoid(float x) { return 1.f / (1.f + __expf(-x)); }
__device__ __forceinline__ float fast_tanh(float x)    { return 1.f - 2.f / (1.f + __expf(2.f * x)); }

// ---------------- heavy barrier: init only (publishes plain-stored weights/q0 via wbl2/inv) ----
__device__ __forceinline__ void grid_barrier(int* flags, int bid, int tid, int epoch) {
    __syncthreads();
    if (tid == 0) {
        __builtin_amdgcn_fence(__ATOMIC_RELEASE, "agent");   // wbl2
        __hip_atomic_store(&flags[bid * 32], epoch, __ATOMIC_RELAXED, __HIP_MEMORY_SCOPE_AGENT);
    }
    if (tid < NBLK) {
        int guard = 0;
        while (__hip_atomic_load(&flags[tid * 32], __ATOMIC_RELAXED, __HIP_MEMORY_SCOPE_AGENT) < epoch) {
            __builtin_amdgcn_s_sleep(32);
            if (++guard > (1 << 17)) break;
        }
    }
    __syncthreads();
    if (tid == 0) __builtin_amdgcn_fence(__ATOMIC_ACQUIRE, "agent");  // inv
    __syncthreads();
}

// ---------------- light barrier: per-step. NO cache fences (round-1/4 proven semantics). ---
// Cumulative distributed arrival: block bid adds 1 to cnt[bid&7] each step; sum >= 256*k
// implies every block arrived k times (monotone induction). No reset, no staleness.
// q coherence: sc0|sc1 stores (LLC), drained by vmcnt(0) BEFORE arrival; sc0|sc1 loads (LLC).
__device__ __forceinline__ void light_barrier(int* cnt, int bid, int tid, int arrivals) {
    asm volatile("s_waitcnt vmcnt(0)" ::: "memory");   // drain this wave's q/out/x vmem
    __syncthreads();
    if (tid == 0)
        __hip_atomic_fetch_add(&cnt[(bid & 7) * 32], 1, __ATOMIC_RELAXED, __HIP_MEMORY_SCOPE_AGENT);
    if (tid < 64) {                                    // one wave gathers 8 lines + shfl-reduce
        const int target = arrivals * NBLK;
        int guard = 0;
        for (;;) {
            int v = (tid < 8)
                ? __hip_atomic_load(&cnt[tid * 32], __ATOMIC_RELAXED, __HIP_MEMORY_SCOPE_AGENT) : 0;
            v += __shfl_xor(v, 4);
            v += __shfl_xor(v, 2);
            v += __shfl_xor(v, 1);
            if (__builtin_amdgcn_readfirstlane(v) >= target) break;
            __builtin_amdgcn_s_sleep(8);
            if (++guard > (1 << 17)) break;
        }
    }
    __syncthreads();
}

#define MFMA16(a, b, c)  __builtin_amdgcn_mfma_f32_16x16x32_bf16((a), (b), (c), 0, 0, 0)
#define MFMAF8(a, b, c)  __builtin_amdgcn_mfma_f32_16x16x32_fp8_fp8((a), (b), (c), 0, 0, 0)

// LLC-coherent q load: 16B = one lane's B-fragments for TWO k-tiles (supertile layout).
#define QLD4(dst, ptr, off) \
    asm volatile("global_load_dwordx4 %0, %1, off offset:" #off " sc0 sc1" \
                 : "=v"(dst) : "v"(ptr))
// one supertile = 4 loads (nt=0..3) = 64 nodes x 64 hh worth of fragments for this wave
#define ISSUE_ST(dst, pp) do { \
    QLD4((dst)[0], (pp), 0);    QLD4((dst)[1], (pp), 1024); \
    QLD4((dst)[2], (pp), 2048); QLD4((dst)[3], (pp), 3072); \
} while (0)
// counted wait on the asm loads; sched_barrier stops MFMAs hoisting above it (rule #18)
#define WAITV(n) do { asm volatile("s_waitcnt vmcnt(" #n ")" ::: "memory"); \
                      __builtin_amdgcn_sched_barrier(0); } while (0)

// 256 blocks on 256 CUs (1 block/CU via 93KB LDS) => all resident => flag barrier safe.
// ws poisoned 0xAA => flags start negative; cnt zeroed by block 0 pre-heavy-barrier.
__global__ __launch_bounds__(NTHR, 1) void glstm_kernel(
    const float* __restrict__ x,      // [4096][128][32]
    const float* __restrict__ adj,    // [4096][4096]
    const float* __restrict__ w_ih,   // [32][256]
    const float* __restrict__ w_hh,   // [64][256]
    const float* __restrict__ bias,   // [256]
    const float* __restrict__ w_q,    // [64][64]
    const float* __restrict__ bias_q, // [64]
    float* __restrict__ out,          // [4096][128][64]
    unsigned char* __restrict__ ws)
{
    const int tid  = threadIdx.x;
    const int bid  = blockIdx.x;
    const int wave = tid >> 6;
    const int lane = tid & 63;
    const int l15  = lane & 15;
    const int quad = lane >> 4;
    const int rowbase = bid * ROWS;

    int* flags = (int*)(ws + WS_FLAGS);
    int* cnt   = (int*)(ws + WS_SYNC);
    unsigned short* Wt  = (unsigned short*)(ws + WS_WT);
    unsigned short* Wqt = (unsigned short*)(ws + WS_WQT);
    unsigned char* qb0 = ws + WS_Q0;
    unsigned char* qb1 = ws + WS_Q1;

    extern __shared__ unsigned char smem[];
    unsigned char* adj_lds = smem;                                   // [16][4112] fp8 (x4096 scale)
    float* gate_lds = (float*)(smem + ADJ_BYTES);                    // [4][16][64]
    float* s_lds    = (float*)(smem + ADJ_BYTES + GATE_BYTES);       // [16][66]
    float* c_lds    = (float*)(smem + ADJ_BYTES + GATE_BYTES + S_BYTES);   // [16][64]
    unsigned short* h_lds = (unsigned short*)(smem + ADJ_BYTES + GATE_BYTES + S_BYTES + C_BYTES); // [16][72]

    // ---------------- init: weights, q0 (fp8 supertiles), zero state/counters, adj->LDS -----
    if (tid < 96) {
        float v = (tid < 32) ? w_ih[tid * 256 + bid] : w_hh[(tid - 32) * 256 + bid];
        Wt[bid * 96 + tid] = f2bf(v);
    }
    if (bid < 64 && tid < 64) Wqt[bid * 64 + tid] = f2bf(w_q[tid * 64 + bid]);
    if (bid == 0 && tid < 8) cnt[tid * 32] = 0;              // cumulative counters start at 0
    for (int idx = tid; idx < ROWS * 64; idx += NTHR) {      // q0 = tanh(bq), supertile layout
        int r = idx >> 6, hh = idx & 63;
        int n = rowbase + r, no = n & 63;
        float v = fast_tanh(bias_q[hh]);
        qb0[(size_t)(n >> 6) * 4096 + (hh >> 4) * 1024 + (hh & 15) * 64
            + ((no >> 3) & 3) * 16 + (no >> 5) * 8 + (no & 7)]
            = (unsigned char)(__builtin_amdgcn_cvt_pk_fp8_f32(v, v, 0, false) & 0xFF);
    }
    for (int idx = tid; idx < ROWS * 64; idx += NTHR) {
        int r = idx >> 6, cc = idx & 63;
        c_lds[r * 64 + cc] = 0.f;
        s_lds[r * 66 + cc] = 0.f;
        h_lds[r * 72 + cc] = 0;
    }
    // adj -> LDS as fp8 e4m3, pre-scaled by 2^12 so [0,1/4096) maps into e4m3 range
    for (int idx = tid; idx < ROWS * (N_NODES / 2); idx += NTHR) {
        int r = idx >> 11, c2 = idx & (N_NODES / 2 - 1);
        f32x2 av = *(const f32x2*)(adj + (size_t)(rowbase + r) * N_NODES + c2 * 2);
        int pk = __builtin_amdgcn_cvt_pk_fp8_f32(av[0] * 4096.f, av[1] * 4096.f, 0, false);
        *(unsigned short*)(adj_lds + r * ADJ_STRIDE_B + c2 * 2) = (unsigned short)pk;
    }
    grid_barrier(flags, bid, tid, 1);        // ONLY heavy barrier: publishes Wt/Wqt/qb0/cnt

    // ---------------- hoist weight fragments into registers ----------------
    const int g    = wave >> 1;        // gate 0..3
    const int half = wave & 1;
    const int nc0  = g * 64 + half * 32 + l15;
    short8 wA[2][3];
#pragma unroll
    for (int nt = 0; nt < 2; ++nt)
#pragma unroll
        for (int kk = 0; kk < 3; ++kk)
            wA[nt][kk] = *(const short8*)(Wt + (nc0 + nt * 16) * 96 + kk * 32 + quad * 8);
    const float bv0 = bias[nc0], bv1 = bias[nc0 + 16];
    const int hhq = (wave & 3) * 16 + l15;
    short8 wQ[2];
#pragma unroll
    for (int kk = 0; kk < 2; ++kk)
        wQ[kk] = *(const short8*)(Wqt + hhq * 64 + kk * 32 + quad * 8);
    const float bqv = bias_q[hhq];

    const float* xlane = x + (size_t)(rowbase + l15) * T_STEPS * 32 + quad * 8;
    const unsigned char* albase = adj_lds + l15 * ADJ_STRIDE_B + wave * 512 + quad * 8;
    // q store byte offset (supertile layout), waves 0..3: node block is contiguous 4 bytes
    const int no0 = ((bid & 3) << 4) + (quad << 2);
    const size_t qdoff = (size_t)(bid >> 2) * 4096 + (size_t)(wave & 3) * 1024
                       + (size_t)l15 * 64 + ((no0 >> 3) & 3) * 16 + (no0 >> 5) * 8 + (no0 & 7);

    f32x4 xa = *(const f32x4*)(xlane);          // x_0 fragment
    f32x4 xb = *(const f32x4*)(xlane + 4);

    // ---------------- Phase A: gates = [x_t | h] @ W + b (block-local, bf16 MFMA) ----------
    auto phaseA = [&]() {
        f32x4 acc0 = {0.f, 0.f, 0.f, 0.f};
        f32x4 acc1 = {0.f, 0.f, 0.f, 0.f};
        short8 a0 = cvt8_trunc_v(xa, xb);
        acc0 = MFMA16(a0, wA[0][0], acc0);
        acc1 = MFMA16(a0, wA[1][0], acc1);
#pragma unroll
        for (int kk = 1; kk < 3; ++kk) {
            short8 a = *(const short8*)(h_lds + l15 * 72 + (kk - 1) * 32 + quad * 8);
            acc0 = MFMA16(a, wA[0][kk], acc0);
            acc1 = MFMA16(a, wA[1][kk], acc1);
        }
#pragma unroll
        for (int nt = 0; nt < 2; ++nt) {
            f32x4 acc = nt ? acc1 : acc0;
            float bv  = nt ? bv1 : bv0;
            int colg  = half * 32 + nt * 16 + l15;
#pragma unroll
            for (int r = 0; r < 4; ++r) {
                float v = acc[r] + bv;
                v = (g == 2) ? fast_tanh(v) : fast_sigmoid(v);
                gate_lds[(g * 16 + quad * 4 + r) * 64 + colg] = v;
            }
        }
    };

    phaseA();                                   // gates for t=0 (h=0)
    xa = *(const f32x4*)(xlane + 32);           // prefetch x_1
    xb = *(const f32x4*)(xlane + 36);

    for (int t = 0; t < T_STEPS; ++t) {
        const unsigned char* qcur = (t & 1) ? qb1 : qb0;
        unsigned char*       qnxt = (t & 1) ? qb0 : qb1;

        // ------ Phase B: s += adj[rows,:] @ q_t (fp8 MFMA; 32 x 16B requests, 2-ahead) ------
        {
            f32x4 acc[4];
#pragma unroll
            for (int nt = 0; nt < 4; ++nt) acc[nt] = (f32x4){0.f, 0.f, 0.f, 0.f};
            // wave owns 8 supertiles: [wave*8, wave*8+8); lane fragment at l15*64 + quad*16
            const unsigned char* qp = qcur + ((size_t)wave << 15) + (l15 << 6) + (quad << 4);
            lx2 buf[3][4];
            ISSUE_ST(buf[0], qp);
            ISSUE_ST(buf[1], qp + 4096);
#pragma unroll
            for (int gg = 0; gg < 8; ++gg) {
                if (gg < 6) { const unsigned char* pg = qp + (gg + 2) * 4096; ISSUE_ST(buf[(gg + 2) % 3], pg); }
                long a0_ = *(const long*)(albase + gg * 64);        // kt = 2*gg   (adj, LDS)
                long a1_ = *(const long*)(albase + gg * 64 + 32);   // kt = 2*gg+1
                if (gg < 6)       WAITV(8);
                else if (gg == 6) WAITV(4);
                else              WAITV(0);
                acc[0] = MFMAF8(a0_, buf[gg % 3][0][0], acc[0]);
                acc[1] = MFMAF8(a0_, buf[gg % 3][1][0], acc[1]);
                acc[2] = MFMAF8(a0_, buf[gg % 3][2][0], acc[2]);
                acc[3] = MFMAF8(a0_, buf[gg % 3][3][0], acc[3]);
                acc[0] = MFMAF8(a1_, buf[gg % 3][0][1], acc[0]);
                acc[1] = MFMAF8(a1_, buf[gg % 3][1][1], acc[1]);
                acc[2] = MFMAF8(a1_, buf[gg % 3][2][1], acc[2]);
                acc[3] = MFMAF8(a1_, buf[gg % 3][3][1], acc[3]);
            }
            // rescale (adj was x4096 in fp8) and reduce across waves
#pragma unroll
            for (int nt = 0; nt < 4; ++nt)
#pragma unroll
                for (int r = 0; r < 4; ++r)
                    atomicAdd(&s_lds[(quad * 4 + r) * 66 + nt * 16 + l15],
                              acc[nt][r] * (1.0f / 4096.0f));
        }
        __syncthreads();

        // ---------------- Phase C: state update + h output (fp32), reset s ----------------
        {
            const int r  = tid >> 5;
            const int c0 = (tid & 31) * 2;
            float hn[2];
#pragma unroll
            for (int j = 0; j < 2; ++j) {
                int cc = c0 + j;
                float s = s_lds[r * 66 + cc];
                s_lds[r * 66 + cc] = 0.f;
                float iv = gate_lds[(0 * 16 + r) * 64 + cc];
                float fv = gate_lds[(1 * 16 + r) * 64 + cc];
                float gv = gate_lds[(2 * 16 + r) * 64 + cc];
                float ov = gate_lds[(3 * 16 + r) * 64 + cc];
                float cn = fv * (c_lds[r * 64 + cc] + s) + iv * gv;
                hn[j] = ov * fast_tanh(cn);
                c_lds[r * 64 + cc] = cn;
            }
            us2 hv; hv[0] = f2bf(hn[0]); hv[1] = f2bf(hn[1]);
            *(us2*)(h_lds + r * 72 + c0) = hv;
            *(f32x2*)(out + ((size_t)(rowbase + r) * T_STEPS + t) * H_DIM + c0) = (f32x2){hn[0], hn[1]};
        }
        __syncthreads();

        if (t < T_STEPS - 1) {
            // -------- Phase D: q_{t+1} = tanh(h @ Wq + bq) -> fp8, sc1 store (supertile) -----
            if (wave < 4) {
                f32x4 acc = {0.f, 0.f, 0.f, 0.f};
#pragma unroll
                for (int kk = 0; kk < 2; ++kk) {
                    short8 a = *(const short8*)(h_lds + l15 * 72 + kk * 32 + quad * 8);
                    acc = MFMA16(a, wQ[kk], acc);
                }
                float q0 = fast_tanh(acc[0] + bqv), q1 = fast_tanh(acc[1] + bqv);
                float q2 = fast_tanh(acc[2] + bqv), q3 = fast_tanh(acc[3] + bqv);
                int pk = __builtin_amdgcn_cvt_pk_fp8_f32(q0, q1, 0, false);
                pk     = __builtin_amdgcn_cvt_pk_fp8_f32(q2, q3, pk, true);
                unsigned char* qdst = qnxt + qdoff;
                asm volatile("global_store_dword %0, %1, off sc0 sc1" :: "v"(qdst), "v"(pk) : "memory");
            }
            phaseA();                                        // gates for t+1 (off critical path)
            if (t < T_STEPS - 2) {
                xa = *(const f32x4*)(xlane + (t + 2) * 32);  // prefetch x_{t+2}
                xb = *(const f32x4*)(xlane + (t + 2) * 32 + 4);
            }
            light_barrier(cnt, bid, tid, t + 1);
        }
    }
}

extern "C" void kernel_launch(void* const* d_in, const int* in_sizes, int n_in,
                              void* d_out, int out_size, void* d_ws, size_t ws_size,
                              hipStream_t stream) {
    if (ws_size < WS_NEED) return;
    const float* x      = (const float*)d_in[0];
    const float* adj    = (const float*)d_in[1];
    const float* w_ih   = (const float*)d_in[2];
    const float* w_hh   = (const float*)d_in[3];
    const float* bias   = (const float*)d_in[4];
    const float* w_q    = (const float*)d_in[5];
    const float* bias_q = (const float*)d_in[6];
    float* o = (float*)d_out;
    unsigned char* w = (unsigned char*)d_ws;

    hipFuncSetAttribute((const void*)glstm_kernel,
                        hipFuncAttributeMaxDynamicSharedMemorySize, SMEM_TOT);
    glstm_kernel<<<NBLK, NTHR, SMEM_TOT, stream>>>(x, adj, w_ih, w_hh, bias, w_q, bias_q, o, w);
}

// Round 6
// 2351.311 us; speedup vs baseline: 1.3209x; 1.0829x over previous
//
#include <hip/hip_runtime.h>

typedef __attribute__((ext_vector_type(8))) short short8;
typedef __attribute__((ext_vector_type(4))) float f32x4;
typedef __attribute__((ext_vector_type(2))) float f32x2;
typedef __attribute__((ext_vector_type(2))) unsigned short us2;
typedef __attribute__((ext_vector_type(2))) long lx2;     // 16B (avoid HIP's long2)

#define N_NODES 4096
#define T_STEPS 128
#define H_DIM   64
#define NBLK    256
#define NTHR    512      // 8 waves
#define ROWS    16       // graph rows per block

// workspace layout (bytes) — same envelope as the proven round-1/4/5 layout
#define WS_FLAGS 0u          // 256 flags, 128B apart = 32 KB (heavy init barrier only)
#define WS_WT    32768u      // Wt[256][96] bf16 (combined [Wih;Whh] transposed)
#define WS_WQT   81920u      // Wqt[64][64] bf16
#define WS_SYNC  90112u      // (unused this round)
#define WS_Q0    98304u      // q fp8 supertiles, 256 KB (layout: see Phase B/D)
#define WS_Q1    360448u
#define WS_LFLAG 622592u     // per-block cumulative step flags, 256 x 128B = 32 KB
#define WS_NEED  1146880u

// dynamic LDS layout (adj fp8: 16 rows x (4096 + 16 pad) bytes)
#define ADJ_STRIDE_B 4112u
#define ADJ_BYTES  (16u * ADJ_STRIDE_B)             // 65792
#define GATE_BYTES 16384u                // [4][16][64] f32
#define S_BYTES    4224u                 // [16][66] f32
#define C_BYTES    4096u                 // [16][64] f32
#define H_BYTES    2304u                 // [16][72] bf16
#define SMEM_TOT   (ADJ_BYTES + GATE_BYTES + S_BYTES + C_BYTES + H_BYTES)   // 92800

__device__ __forceinline__ unsigned short f2bf(float f) {   // RNE fp32->bf16
    unsigned x = __float_as_uint(f);
    unsigned r = ((x >> 16) & 1u) + 0x7fffu;
    return (unsigned short)((x + r) >> 16);
}
__device__ __forceinline__ short8 cvt8_trunc_v(f32x4 a, f32x4 b) {  // truncating pack f32->bf16 x8
    union { unsigned u[4]; short8 s; } cv;
    cv.u[0] = __builtin_amdgcn_perm(__float_as_uint(a[1]), __float_as_uint(a[0]), 0x07060302u);
    cv.u[1] = __builtin_amdgcn_perm(__float_as_uint(a[3]), __float_as_uint(a[2]), 0x07060302u);
    cv.u[2] = __builtin_amdgcn_perm(__float_as_uint(b[1]), __float_as_uint(b[0]), 0x07060302u);
    cv.u[3] = __builtin_amdgcn_perm(__float_as_uint(b[3]), __float_as_uint(b[2]), 0x07060302u);
    return cv.s;
}
__device__ __forceinline__ float fast_sigmoid(float x) { return 1.f / (1.f + __expf(-x)); }
__device__ __forceinline__ float fast_tanh(float x)    { return 1.f - 2.f / (1.f + __expf(2.f * x)); }

// ---------------- heavy barrier: init only (publishes plain-stored weights/q0 via wbl2/inv) ----
__device__ __forceinline__ void grid_barrier(int* flags, int bid, int tid, int epoch) {
    __syncthreads();
    if (tid == 0) {
        __builtin_amdgcn_fence(__ATOMIC_RELEASE, "agent");   // wbl2
        __hip_atomic_store(&flags[bid * 32], epoch, __ATOMIC_RELAXED, __HIP_MEMORY_SCOPE_AGENT);
    }
    if (tid < NBLK) {
        int guard = 0;
        while (__hip_atomic_load(&flags[tid * 32], __ATOMIC_RELAXED, __HIP_MEMORY_SCOPE_AGENT) < epoch) {
            __builtin_amdgcn_s_sleep(32);
            if (++guard > (1 << 17)) break;
        }
    }
    __syncthreads();
    if (tid == 0) __builtin_amdgcn_fence(__ATOMIC_ACQUIRE, "agent");  // inv
    __syncthreads();
}

#define MFMA16(a, b, c)  __builtin_amdgcn_mfma_f32_16x16x32_bf16((a), (b), (c), 0, 0, 0)
#define MFMAF8(a, b, c)  __builtin_amdgcn_mfma_f32_16x16x32_fp8_fp8((a), (b), (c), 0, 0, 0)

// LLC-coherent q load: 16B = one lane's B-fragments for TWO k-tiles (supertile layout).
#define QLD4(dst, ptr, off) \
    asm volatile("global_load_dwordx4 %0, %1, off offset:" #off " sc0 sc1" \
                 : "=v"(dst) : "v"(ptr))
// one supertile = 4 loads (nt=0..3) = 64 nodes x 64 hh worth of fragments for this wave
#define ISSUE_ST(dst, pp) do { \
    QLD4((dst)[0], (pp), 0);    QLD4((dst)[1], (pp), 1024); \
    QLD4((dst)[2], (pp), 2048); QLD4((dst)[3], (pp), 3072); \
} while (0)
// counted wait on the asm loads; sched_barrier stops MFMAs hoisting above it (rule #18)
#define WAITV(n) do { asm volatile("s_waitcnt vmcnt(" #n ")" ::: "memory"); \
                      __builtin_amdgcn_sched_barrier(0); } while (0)

// 256 blocks on 256 CUs (1 block/CU via 93KB LDS) => all resident => flag sync safe.
// NO per-step grid rendezvous: producer/consumer flag pipelining.
//   lflags[b] = number of completed steps by block b (cumulative, monotone; 0 after init).
//   B_t of wave w waits for lflags[w*32..w*32+31] >= t  (its producers' D_{t-1} drained).
//   Write-safety for D_t (overwrite of q_{t-1} slot): my block's 8 waves collectively
//   observed ALL 256 flags >= t during B_t, and D_t follows B_t via __syncthreads.
//   Flag set only after vmcnt(0)+__syncthreads drains all of this block's sc1 q stores.
__global__ __launch_bounds__(NTHR, 1) void glstm_kernel(
    const float* __restrict__ x,      // [4096][128][32]
    const float* __restrict__ adj,    // [4096][4096]
    const float* __restrict__ w_ih,   // [32][256]
    const float* __restrict__ w_hh,   // [64][256]
    const float* __restrict__ bias,   // [256]
    const float* __restrict__ w_q,    // [64][64]
    const float* __restrict__ bias_q, // [64]
    float* __restrict__ out,          // [4096][128][64]
    unsigned char* __restrict__ ws)
{
    const int tid  = threadIdx.x;
    const int bid  = blockIdx.x;
    const int wave = tid >> 6;
    const int lane = tid & 63;
    const int l15  = lane & 15;
    const int quad = lane >> 4;
    const int rowbase = bid * ROWS;

    int* flags  = (int*)(ws + WS_FLAGS);
    int* lflags = (int*)(ws + WS_LFLAG);
    unsigned short* Wt  = (unsigned short*)(ws + WS_WT);
    unsigned short* Wqt = (unsigned short*)(ws + WS_WQT);
    unsigned char* qb0 = ws + WS_Q0;
    unsigned char* qb1 = ws + WS_Q1;

    extern __shared__ unsigned char smem[];
    unsigned char* adj_lds = smem;                                   // [16][4112] fp8 (x4096 scale)
    float* gate_lds = (float*)(smem + ADJ_BYTES);                    // [4][16][64]
    float* s_lds    = (float*)(smem + ADJ_BYTES + GATE_BYTES);       // [16][66]
    float* c_lds    = (float*)(smem + ADJ_BYTES + GATE_BYTES + S_BYTES);   // [16][64]
    unsigned short* h_lds = (unsigned short*)(smem + ADJ_BYTES + GATE_BYTES + S_BYTES + C_BYTES); // [16][72]

    // ---------------- init: weights, q0 (fp8 supertiles), zero state/flags, adj->LDS --------
    if (tid < 96) {
        float v = (tid < 32) ? w_ih[tid * 256 + bid] : w_hh[(tid - 32) * 256 + bid];
        Wt[bid * 96 + tid] = f2bf(v);
    }
    if (bid < 64 && tid < 64) Wqt[bid * 64 + tid] = f2bf(w_q[tid * 64 + bid]);
    if (tid == 0) lflags[bid * 32] = 0;                      // own step-flag: 0 steps done
    for (int idx = tid; idx < ROWS * 64; idx += NTHR) {      // q0 = tanh(bq), supertile layout
        int r = idx >> 6, hh = idx & 63;
        int n = rowbase + r, no = n & 63;
        float v = fast_tanh(bias_q[hh]);
        qb0[(size_t)(n >> 6) * 4096 + (hh >> 4) * 1024 + (hh & 15) * 64
            + ((no >> 3) & 3) * 16 + (no >> 5) * 8 + (no & 7)]
            = (unsigned char)(__builtin_amdgcn_cvt_pk_fp8_f32(v, v, 0, false) & 0xFF);
    }
    for (int idx = tid; idx < ROWS * 64; idx += NTHR) {
        int r = idx >> 6, cc = idx & 63;
        c_lds[r * 64 + cc] = 0.f;
        s_lds[r * 66 + cc] = 0.f;
        h_lds[r * 72 + cc] = 0;
    }
    // adj -> LDS as fp8 e4m3, pre-scaled by 2^12 so [0,1/4096) maps into e4m3 range
    for (int idx = tid; idx < ROWS * (N_NODES / 2); idx += NTHR) {
        int r = idx >> 11, c2 = idx & (N_NODES / 2 - 1);
        f32x2 av = *(const f32x2*)(adj + (size_t)(rowbase + r) * N_NODES + c2 * 2);
        int pk = __builtin_amdgcn_cvt_pk_fp8_f32(av[0] * 4096.f, av[1] * 4096.f, 0, false);
        *(unsigned short*)(adj_lds + r * ADJ_STRIDE_B + c2 * 2) = (unsigned short)pk;
    }
    grid_barrier(flags, bid, tid, 1);        // ONLY heavy barrier: publishes Wt/Wqt/qb0/lflags

    // ---------------- hoist weight fragments into registers ----------------
    const int g    = wave >> 1;        // gate 0..3
    const int half = wave & 1;
    const int nc0  = g * 64 + half * 32 + l15;
    short8 wA[2][3];
#pragma unroll
    for (int nt = 0; nt < 2; ++nt)
#pragma unroll
        for (int kk = 0; kk < 3; ++kk)
            wA[nt][kk] = *(const short8*)(Wt + (nc0 + nt * 16) * 96 + kk * 32 + quad * 8);
    const float bv0 = bias[nc0], bv1 = bias[nc0 + 16];
    const int hhq = (wave & 3) * 16 + l15;
    short8 wQ[2];
#pragma unroll
    for (int kk = 0; kk < 2; ++kk)
        wQ[kk] = *(const short8*)(Wqt + hhq * 64 + kk * 32 + quad * 8);
    const float bqv = bias_q[hhq];

    const float* xlane = x + (size_t)(rowbase + l15) * T_STEPS * 32 + quad * 8;
    const unsigned char* albase = adj_lds + l15 * ADJ_STRIDE_B + wave * 512 + quad * 8;
    // q store byte offset (supertile layout), waves 0..3: node block is contiguous 4 bytes
    const int no0 = ((bid & 3) << 4) + (quad << 2);
    const size_t qdoff = (size_t)(bid >> 2) * 4096 + (size_t)(wave & 3) * 1024
                       + (size_t)l15 * 64 + ((no0 >> 3) & 3) * 16 + (no0 >> 5) * 8 + (no0 & 7);
    // producer block polled by this wave's lane (lane<32): blocks wave*32 .. wave*32+31
    const int prodb = (wave << 5) + (lane & 31);

    f32x4 xa = *(const f32x4*)(xlane);          // x_0 fragment
    f32x4 xb = *(const f32x4*)(xlane + 4);

    // ---------------- Phase A: gates = [x_t | h] @ W + b (block-local, bf16 MFMA) ----------
    auto phaseA = [&]() {
        f32x4 acc0 = {0.f, 0.f, 0.f, 0.f};
        f32x4 acc1 = {0.f, 0.f, 0.f, 0.f};
        short8 a0 = cvt8_trunc_v(xa, xb);
        acc0 = MFMA16(a0, wA[0][0], acc0);
        acc1 = MFMA16(a0, wA[1][0], acc1);
#pragma unroll
        for (int kk = 1; kk < 3; ++kk) {
            short8 a = *(const short8*)(h_lds + l15 * 72 + (kk - 1) * 32 + quad * 8);
            acc0 = MFMA16(a, wA[0][kk], acc0);
            acc1 = MFMA16(a, wA[1][kk], acc1);
        }
#pragma unroll
        for (int nt = 0; nt < 2; ++nt) {
            f32x4 acc = nt ? acc1 : acc0;
            float bv  = nt ? bv1 : bv0;
            int colg  = half * 32 + nt * 16 + l15;
#pragma unroll
            for (int r = 0; r < 4; ++r) {
                float v = acc[r] + bv;
                v = (g == 2) ? fast_tanh(v) : fast_sigmoid(v);
                gate_lds[(g * 16 + quad * 4 + r) * 64 + colg] = v;
            }
        }
    };

    phaseA();                                   // gates for t=0 (h=0)
    xa = *(const f32x4*)(xlane + 32);           // prefetch x_1
    xb = *(const f32x4*)(xlane + 36);

    const int rot = bid & 7;                    // supertile start rotation (burst spreading)

    for (int t = 0; t < T_STEPS; ++t) {
        const unsigned char* qcur = (t & 1) ? qb1 : qb0;
        unsigned char*       qnxt = (t & 1) ? qb0 : qb1;

        // ------ Phase B: wait own producers, then s += adj[rows,:] @ q_t (fp8 MFMA) ---------
        {
            // per-wave producer gate: lanes 0..31 poll 32 flags; exec-mask loop == __all
            if (lane < 32) {
                int guard = 0;
                while (__hip_atomic_load(&lflags[prodb * 32],
                                         __ATOMIC_RELAXED, __HIP_MEMORY_SCOPE_AGENT) < t) {
                    __builtin_amdgcn_s_sleep(4);
                    if (++guard > (1 << 17)) break;
                }
            }
            f32x4 acc[4];
#pragma unroll
            for (int nt = 0; nt < 4; ++nt) acc[nt] = (f32x4){0.f, 0.f, 0.f, 0.f};
            // wave owns 8 supertiles [wave*8, wave*8+8), processed in bid-rotated order
            const unsigned char* qp = qcur + ((size_t)wave << 15) + (l15 << 6) + (quad << 4);
            lx2 buf[3][4];
            ISSUE_ST(buf[0], qp + (size_t)(((0 + rot) & 7)) * 4096);
            ISSUE_ST(buf[1], qp + (size_t)(((1 + rot) & 7)) * 4096);
#pragma unroll
            for (int gg = 0; gg < 8; ++gg) {
                const int s = (gg + rot) & 7;
                if (gg < 6) {
                    const int s2 = (gg + 2 + rot) & 7;
                    ISSUE_ST(buf[(gg + 2) % 3], qp + (size_t)s2 * 4096);
                }
                long a0_ = *(const long*)(albase + s * 64);        // kt = 2*s   (adj, LDS)
                long a1_ = *(const long*)(albase + s * 64 + 32);   // kt = 2*s+1
                if (gg < 6)       WAITV(8);
                else if (gg == 6) WAITV(4);
                else              WAITV(0);
                acc[0] = MFMAF8(a0_, buf[gg % 3][0][0], acc[0]);
                acc[1] = MFMAF8(a0_, buf[gg % 3][1][0], acc[1]);
                acc[2] = MFMAF8(a0_, buf[gg % 3][2][0], acc[2]);
                acc[3] = MFMAF8(a0_, buf[gg % 3][3][0], acc[3]);
                acc[0] = MFMAF8(a1_, buf[gg % 3][0][1], acc[0]);
                acc[1] = MFMAF8(a1_, buf[gg % 3][1][1], acc[1]);
                acc[2] = MFMAF8(a1_, buf[gg % 3][2][1], acc[2]);
                acc[3] = MFMAF8(a1_, buf[gg % 3][3][1], acc[3]);
            }
            // rescale (adj was x4096 in fp8) and reduce across waves
#pragma unroll
            for (int nt = 0; nt < 4; ++nt)
#pragma unroll
                for (int r = 0; r < 4; ++r)
                    atomicAdd(&s_lds[(quad * 4 + r) * 66 + nt * 16 + l15],
                              acc[nt][r] * (1.0f / 4096.0f));
        }
        __syncthreads();

        // ---------------- Phase C: state update + h output (fp32), reset s ----------------
        {
            const int r  = tid >> 5;
            const int c0 = (tid & 31) * 2;
            float hn[2];
#pragma unroll
            for (int j = 0; j < 2; ++j) {
                int cc = c0 + j;
                float s = s_lds[r * 66 + cc];
                s_lds[r * 66 + cc] = 0.f;
                float iv = gate_lds[(0 * 16 + r) * 64 + cc];
                float fv = gate_lds[(1 * 16 + r) * 64 + cc];
                float gv = gate_lds[(2 * 16 + r) * 64 + cc];
                float ov = gate_lds[(3 * 16 + r) * 64 + cc];
                float cn = fv * (c_lds[r * 64 + cc] + s) + iv * gv;
                hn[j] = ov * fast_tanh(cn);
                c_lds[r * 64 + cc] = cn;
            }
            us2 hv; hv[0] = f2bf(hn[0]); hv[1] = f2bf(hn[1]);
            *(us2*)(h_lds + r * 72 + c0) = hv;
            *(f32x2*)(out + ((size_t)(rowbase + r) * T_STEPS + t) * H_DIM + c0) = (f32x2){hn[0], hn[1]};
        }
        __syncthreads();

        if (t < T_STEPS - 1) {
            // -------- Phase D: q_{t+1} = tanh(h @ Wq + bq) -> fp8, sc1 store (supertile) -----
            if (wave < 4) {
                f32x4 acc = {0.f, 0.f, 0.f, 0.f};
#pragma unroll
                for (int kk = 0; kk < 2; ++kk) {
                    short8 a = *(const short8*)(h_lds + l15 * 72 + kk * 32 + quad * 8);
                    acc = MFMA16(a, wQ[kk], acc);
                }
                float q0 = fast_tanh(acc[0] + bqv), q1 = fast_tanh(acc[1] + bqv);
                float q2 = fast_tanh(acc[2] + bqv), q3 = fast_tanh(acc[3] + bqv);
                int pk = __builtin_amdgcn_cvt_pk_fp8_f32(q0, q1, 0, false);
                pk     = __builtin_amdgcn_cvt_pk_fp8_f32(q2, q3, pk, true);
                unsigned char* qdst = qnxt + qdoff;
                asm volatile("global_store_dword %0, %1, off sc0 sc1" :: "v"(qdst), "v"(pk) : "memory");
            }
            phaseA();                                        // gates for t+1 (off critical path)
            if (t < T_STEPS - 2) {
                xa = *(const f32x4*)(xlane + (t + 2) * 32);  // prefetch x_{t+2}
                xb = *(const f32x4*)(xlane + (t + 2) * 32 + 4);
            }
            // -------- publish: all waves' q stores drained, then bump own step flag ----------
            asm volatile("s_waitcnt vmcnt(0)" ::: "memory");
            __syncthreads();
            if (tid == 0)
                __hip_atomic_store(&lflags[bid * 32], t + 1,
                                   __ATOMIC_RELAXED, __HIP_MEMORY_SCOPE_AGENT);
        }
    }
}

extern "C" void kernel_launch(void* const* d_in, const int* in_sizes, int n_in,
                              void* d_out, int out_size, void* d_ws, size_t ws_size,
                              hipStream_t stream) {
    if (ws_size < WS_NEED) return;
    const float* x      = (const float*)d_in[0];
    const float* adj    = (const float*)d_in[1];
    const float* w_ih   = (const float*)d_in[2];
    const float* w_hh   = (const float*)d_in[3];
    const float* bias   = (const float*)d_in[4];
    const float* w_q    = (const float*)d_in[5];
    const float* bias_q = (const float*)d_in[6];
    float* o = (float*)d_out;
    unsigned char* w = (unsigned char*)d_ws;

    hipFuncSetAttribute((const void*)glstm_kernel,
                        hipFuncAttributeMaxDynamicSharedMemorySize, SMEM_TOT);
    glstm_kernel<<<NBLK, NTHR, SMEM_TOT, stream>>>(x, adj, w_ih, w_hh, bias, w_q, bias_q, o, w);
}

// Round 7
// 2127.625 us; speedup vs baseline: 1.4598x; 1.1051x over previous
//
#include <hip/hip_runtime.h>

typedef __attribute__((ext_vector_type(8))) short short8;
typedef __attribute__((ext_vector_type(4))) float f32x4;
typedef __attribute__((ext_vector_type(2))) float f32x2;
typedef __attribute__((ext_vector_type(2))) unsigned short us2;
typedef __attribute__((ext_vector_type(2))) long lx2;     // 16B (avoid HIP's long2)

#define N_NODES 4096
#define T_STEPS 128
#define H_DIM   64
#define NBLK    256
#define NTHR    512      // 8 waves
#define ROWS    16       // graph rows per block

// workspace layout (bytes) — same envelope as the proven round-1/4/5/6 layout
#define WS_FLAGS 0u          // 256 flags, 128B apart = 32 KB (heavy init barrier only)
#define WS_WT    32768u      // Wt[256][96] bf16 (combined [Wih;Whh] transposed)
#define WS_WQT   81920u      // Wqt[64][64] bf16
#define WS_Q0    98304u      // q fp8 supertiles, 256 KB (layout: see Phase B/D)
#define WS_Q1    360448u
#define WS_LFLAG 622592u     // per-block cumulative step flags, 256 x 128B = 32 KB
#define WS_NEED  1146880u

// dynamic LDS layout (adj fp8: 16 rows x (4096 + 16 pad) bytes)
#define ADJ_STRIDE_B 4112u
#define ADJ_BYTES  (16u * ADJ_STRIDE_B)             // 65792
#define GATE_BYTES 16384u                // [4][16][64] f32
#define S_BYTES    4224u                 // [16][66] f32
#define C_BYTES    4096u                 // [16][64] f32
#define H_BYTES    2304u                 // [16][72] bf16
#define SMEM_TOT   (ADJ_BYTES + GATE_BYTES + S_BYTES + C_BYTES + H_BYTES)   // 92800

__device__ __forceinline__ unsigned short f2bf(float f) {   // RNE fp32->bf16
    unsigned x = __float_as_uint(f);
    unsigned r = ((x >> 16) & 1u) + 0x7fffu;
    return (unsigned short)((x + r) >> 16);
}
__device__ __forceinline__ short8 cvt8_trunc_v(f32x4 a, f32x4 b) {  // truncating pack f32->bf16 x8
    union { unsigned u[4]; short8 s; } cv;
    cv.u[0] = __builtin_amdgcn_perm(__float_as_uint(a[1]), __float_as_uint(a[0]), 0x07060302u);
    cv.u[1] = __builtin_amdgcn_perm(__float_as_uint(a[3]), __float_as_uint(a[2]), 0x07060302u);
    cv.u[2] = __builtin_amdgcn_perm(__float_as_uint(b[1]), __float_as_uint(b[0]), 0x07060302u);
    cv.u[3] = __builtin_amdgcn_perm(__float_as_uint(b[3]), __float_as_uint(b[2]), 0x07060302u);
    return cv.s;
}
__device__ __forceinline__ float fast_sigmoid(float x) { return 1.f / (1.f + __expf(-x)); }
__device__ __forceinline__ float fast_tanh(float x)    { return 1.f - 2.f / (1.f + __expf(2.f * x)); }

// ---------------- heavy barrier: init only (publishes plain-stored weights/q0 via wbl2/inv) ----
__device__ __forceinline__ void grid_barrier(int* flags, int bid, int tid, int epoch) {
    __syncthreads();
    if (tid == 0) {
        __builtin_amdgcn_fence(__ATOMIC_RELEASE, "agent");   // wbl2
        __hip_atomic_store(&flags[bid * 32], epoch, __ATOMIC_RELAXED, __HIP_MEMORY_SCOPE_AGENT);
    }
    if (tid < NBLK) {
        int guard = 0;
        while (__hip_atomic_load(&flags[tid * 32], __ATOMIC_RELAXED, __HIP_MEMORY_SCOPE_AGENT) < epoch) {
            __builtin_amdgcn_s_sleep(32);
            if (++guard > (1 << 17)) break;
        }
    }
    __syncthreads();
    if (tid == 0) __builtin_amdgcn_fence(__ATOMIC_ACQUIRE, "agent");  // inv
    __syncthreads();
}

#define MFMA16(a, b, c)  __builtin_amdgcn_mfma_f32_16x16x32_bf16((a), (b), (c), 0, 0, 0)
#define MFMAF8(a, b, c)  __builtin_amdgcn_mfma_f32_16x16x32_fp8_fp8((a), (b), (c), 0, 0, 0)

// LLC-coherent q load: 16B = one lane's B-fragments for TWO k-tiles (supertile layout).
#define QLD4(dst, ptr, off) \
    asm volatile("global_load_dwordx4 %0, %1, off offset:" #off " sc0 sc1" \
                 : "=v"(dst) : "v"(ptr))
// one supertile = 4 loads (nt=0..3) = 64 nodes x 64 hh worth of fragments for this wave
#define ISSUE_ST(dst, pp) do { \
    QLD4((dst)[0], (pp), 0);    QLD4((dst)[1], (pp), 1024); \
    QLD4((dst)[2], (pp), 2048); QLD4((dst)[3], (pp), 3072); \
} while (0)
// counted wait on the asm loads; sched_barrier stops MFMAs hoisting above it (rule #18)
#define WAITV(n) do { asm volatile("s_waitcnt vmcnt(" #n ")" ::: "memory"); \
                      __builtin_amdgcn_sched_barrier(0); } while (0)
// consume issued-group gg (compile-time), waiting until its 4 loads have landed (W = 28-4*gg)
#define BSTEP(gg, W) do { \
    const int s_ = ((gg) + rot) & 7; \
    long a0_ = *(const long*)(albase + s_ * 64);        /* kt = 2*s   (adj, LDS) */ \
    long a1_ = *(const long*)(albase + s_ * 64 + 32);   /* kt = 2*s+1 */ \
    WAITV(W); \
    acc[0] = MFMAF8(a0_, buf[gg][0][0], acc[0]); \
    acc[1] = MFMAF8(a0_, buf[gg][1][0], acc[1]); \
    acc[2] = MFMAF8(a0_, buf[gg][2][0], acc[2]); \
    acc[3] = MFMAF8(a0_, buf[gg][3][0], acc[3]); \
    acc[0] = MFMAF8(a1_, buf[gg][0][1], acc[0]); \
    acc[1] = MFMAF8(a1_, buf[gg][1][1], acc[1]); \
    acc[2] = MFMAF8(a1_, buf[gg][2][1], acc[2]); \
    acc[3] = MFMAF8(a1_, buf[gg][3][1], acc[3]); \
} while (0)

// 256 blocks on 256 CUs (1 block/CU via 93KB LDS) => all resident => flag sync safe.
// Producer/consumer flag pipelining (no grid rendezvous) — see round-6 comments.
// This round: (1) publish moved BEFORE phaseA/prefetch (off the global critical path);
// (2) Phase B issues all 32 loads up-front (depth-32 pipeline, WAITV ladder 28..0);
// (3) gate poll backoff sleep(8) + explicit WAITV(0) post-gate to clean the vm counter.
__global__ __launch_bounds__(NTHR, 1) void glstm_kernel(
    const float* __restrict__ x,      // [4096][128][32]
    const float* __restrict__ adj,    // [4096][4096]
    const float* __restrict__ w_ih,   // [32][256]
    const float* __restrict__ w_hh,   // [64][256]
    const float* __restrict__ bias,   // [256]
    const float* __restrict__ w_q,    // [64][64]
    const float* __restrict__ bias_q, // [64]
    float* __restrict__ out,          // [4096][128][64]
    unsigned char* __restrict__ ws)
{
    const int tid  = threadIdx.x;
    const int bid  = blockIdx.x;
    const int wave = tid >> 6;
    const int lane = tid & 63;
    const int l15  = lane & 15;
    const int quad = lane >> 4;
    const int rowbase = bid * ROWS;

    int* flags  = (int*)(ws + WS_FLAGS);
    int* lflags = (int*)(ws + WS_LFLAG);
    unsigned short* Wt  = (unsigned short*)(ws + WS_WT);
    unsigned short* Wqt = (unsigned short*)(ws + WS_WQT);
    unsigned char* qb0 = ws + WS_Q0;
    unsigned char* qb1 = ws + WS_Q1;

    extern __shared__ unsigned char smem[];
    unsigned char* adj_lds = smem;                                   // [16][4112] fp8 (x4096 scale)
    float* gate_lds = (float*)(smem + ADJ_BYTES);                    // [4][16][64]
    float* s_lds    = (float*)(smem + ADJ_BYTES + GATE_BYTES);       // [16][66]
    float* c_lds    = (float*)(smem + ADJ_BYTES + GATE_BYTES + S_BYTES);   // [16][64]
    unsigned short* h_lds = (unsigned short*)(smem + ADJ_BYTES + GATE_BYTES + S_BYTES + C_BYTES); // [16][72]

    // ---------------- init: weights, q0 (fp8 supertiles), zero state/flags, adj->LDS --------
    if (tid < 96) {
        float v = (tid < 32) ? w_ih[tid * 256 + bid] : w_hh[(tid - 32) * 256 + bid];
        Wt[bid * 96 + tid] = f2bf(v);
    }
    if (bid < 64 && tid < 64) Wqt[bid * 64 + tid] = f2bf(w_q[tid * 64 + bid]);
    if (tid == 0) lflags[bid * 32] = 0;                      // own step-flag: 0 steps done
    for (int idx = tid; idx < ROWS * 64; idx += NTHR) {      // q0 = tanh(bq), supertile layout
        int r = idx >> 6, hh = idx & 63;
        int n = rowbase + r, no = n & 63;
        float v = fast_tanh(bias_q[hh]);
        qb0[(size_t)(n >> 6) * 4096 + (hh >> 4) * 1024 + (hh & 15) * 64
            + ((no >> 3) & 3) * 16 + (no >> 5) * 8 + (no & 7)]
            = (unsigned char)(__builtin_amdgcn_cvt_pk_fp8_f32(v, v, 0, false) & 0xFF);
    }
    for (int idx = tid; idx < ROWS * 64; idx += NTHR) {
        int r = idx >> 6, cc = idx & 63;
        c_lds[r * 64 + cc] = 0.f;
        s_lds[r * 66 + cc] = 0.f;
        h_lds[r * 72 + cc] = 0;
    }
    // adj -> LDS as fp8 e4m3, pre-scaled by 2^12 so [0,1/4096) maps into e4m3 range
    for (int idx = tid; idx < ROWS * (N_NODES / 2); idx += NTHR) {
        int r = idx >> 11, c2 = idx & (N_NODES / 2 - 1);
        f32x2 av = *(const f32x2*)(adj + (size_t)(rowbase + r) * N_NODES + c2 * 2);
        int pk = __builtin_amdgcn_cvt_pk_fp8_f32(av[0] * 4096.f, av[1] * 4096.f, 0, false);
        *(unsigned short*)(adj_lds + r * ADJ_STRIDE_B + c2 * 2) = (unsigned short)pk;
    }
    grid_barrier(flags, bid, tid, 1);        // ONLY heavy barrier: publishes Wt/Wqt/qb0/lflags

    // ---------------- hoist weight fragments into registers ----------------
    const int g    = wave >> 1;        // gate 0..3
    const int half = wave & 1;
    const int nc0  = g * 64 + half * 32 + l15;
    short8 wA[2][3];
#pragma unroll
    for (int nt = 0; nt < 2; ++nt)
#pragma unroll
        for (int kk = 0; kk < 3; ++kk)
            wA[nt][kk] = *(const short8*)(Wt + (nc0 + nt * 16) * 96 + kk * 32 + quad * 8);
    const float bv0 = bias[nc0], bv1 = bias[nc0 + 16];
    const int hhq = (wave & 3) * 16 + l15;
    short8 wQ[2];
#pragma unroll
    for (int kk = 0; kk < 2; ++kk)
        wQ[kk] = *(const short8*)(Wqt + hhq * 64 + kk * 32 + quad * 8);
    const float bqv = bias_q[hhq];

    const float* xlane = x + (size_t)(rowbase + l15) * T_STEPS * 32 + quad * 8;
    const unsigned char* albase = adj_lds + l15 * ADJ_STRIDE_B + wave * 512 + quad * 8;
    // q store byte offset (supertile layout), waves 0..3: node block is contiguous 4 bytes
    const int no0 = ((bid & 3) << 4) + (quad << 2);
    const size_t qdoff = (size_t)(bid >> 2) * 4096 + (size_t)(wave & 3) * 1024
                       + (size_t)l15 * 64 + ((no0 >> 3) & 3) * 16 + (no0 >> 5) * 8 + (no0 & 7);
    // producer block polled by this wave's lane (lane<32): blocks wave*32 .. wave*32+31
    const int prodb = (wave << 5) + (lane & 31);

    f32x4 xa = *(const f32x4*)(xlane);          // x_0 fragment
    f32x4 xb = *(const f32x4*)(xlane + 4);

    // ---------------- Phase A: gates = [x_t | h] @ W + b (block-local, bf16 MFMA) ----------
    auto phaseA = [&]() {
        f32x4 acc0 = {0.f, 0.f, 0.f, 0.f};
        f32x4 acc1 = {0.f, 0.f, 0.f, 0.f};
        short8 a0 = cvt8_trunc_v(xa, xb);
        acc0 = MFMA16(a0, wA[0][0], acc0);
        acc1 = MFMA16(a0, wA[1][0], acc1);
#pragma unroll
        for (int kk = 1; kk < 3; ++kk) {
            short8 a = *(const short8*)(h_lds + l15 * 72 + (kk - 1) * 32 + quad * 8);
            acc0 = MFMA16(a, wA[0][kk], acc0);
            acc1 = MFMA16(a, wA[1][kk], acc1);
        }
#pragma unroll
        for (int nt = 0; nt < 2; ++nt) {
            f32x4 acc = nt ? acc1 : acc0;
            float bv  = nt ? bv1 : bv0;
            int colg  = half * 32 + nt * 16 + l15;
#pragma unroll
            for (int r = 0; r < 4; ++r) {
                float v = acc[r] + bv;
                v = (g == 2) ? fast_tanh(v) : fast_sigmoid(v);
                gate_lds[(g * 16 + quad * 4 + r) * 64 + colg] = v;
            }
        }
    };

    phaseA();                                   // gates for t=0 (h=0)
    xa = *(const f32x4*)(xlane + 32);           // prefetch x_1
    xb = *(const f32x4*)(xlane + 36);

    const int rot = bid & 7;                    // supertile start rotation (burst spreading)

    for (int t = 0; t < T_STEPS; ++t) {
        const unsigned char* qcur = (t & 1) ? qb1 : qb0;
        unsigned char*       qnxt = (t & 1) ? qb0 : qb1;

        // ------ Phase B: wait own producers, then s += adj[rows,:] @ q_t (fp8 MFMA) ---------
        {
            // per-wave producer gate: lanes 0..31 poll 32 flags; exec-mask loop == __all
            if (lane < 32) {
                int guard = 0;
                while (__hip_atomic_load(&lflags[prodb * 32],
                                         __ATOMIC_RELAXED, __HIP_MEMORY_SCOPE_AGENT) < t) {
                    __builtin_amdgcn_s_sleep(8);
                    if (++guard > (1 << 17)) break;
                }
            }
            WAITV(0);                           // clean vm counter (poll/x-prefetch drained)
            f32x4 acc[4];
#pragma unroll
            for (int nt = 0; nt < 4; ++nt) acc[nt] = (f32x4){0.f, 0.f, 0.f, 0.f};
            // wave owns 8 supertiles [wave*8, wave*8+8), processed in bid-rotated order;
            // ALL 32 loads issued up-front (depth-32 pipeline), consumed via WAITV ladder.
            const unsigned char* qp = qcur + ((size_t)wave << 15) + (l15 << 6) + (quad << 4);
            lx2 buf[8][4];
#pragma unroll
            for (int ii = 0; ii < 8; ++ii)
                ISSUE_ST(buf[ii], qp + (size_t)((ii + rot) & 7) * 4096);
            BSTEP(0, 28); BSTEP(1, 24); BSTEP(2, 20); BSTEP(3, 16);
            BSTEP(4, 12); BSTEP(5, 8);  BSTEP(6, 4);  BSTEP(7, 0);
            // rescale (adj was x4096 in fp8) and reduce across waves
#pragma unroll
            for (int nt = 0; nt < 4; ++nt)
#pragma unroll
                for (int r = 0; r < 4; ++r)
                    atomicAdd(&s_lds[(quad * 4 + r) * 66 + nt * 16 + l15],
                              acc[nt][r] * (1.0f / 4096.0f));
        }
        __syncthreads();

        // ---------------- Phase C: state update + h output (fp32), reset s ----------------
        {
            const int r  = tid >> 5;
            const int c0 = (tid & 31) * 2;
            float hn[2];
#pragma unroll
            for (int j = 0; j < 2; ++j) {
                int cc = c0 + j;
                float s = s_lds[r * 66 + cc];
                s_lds[r * 66 + cc] = 0.f;
                float iv = gate_lds[(0 * 16 + r) * 64 + cc];
                float fv = gate_lds[(1 * 16 + r) * 64 + cc];
                float gv = gate_lds[(2 * 16 + r) * 64 + cc];
                float ov = gate_lds[(3 * 16 + r) * 64 + cc];
                float cn = fv * (c_lds[r * 64 + cc] + s) + iv * gv;
                hn[j] = ov * fast_tanh(cn);
                c_lds[r * 64 + cc] = cn;
            }
            us2 hv; hv[0] = f2bf(hn[0]); hv[1] = f2bf(hn[1]);
            *(us2*)(h_lds + r * 72 + c0) = hv;
            *(f32x2*)(out + ((size_t)(rowbase + r) * T_STEPS + t) * H_DIM + c0) = (f32x2){hn[0], hn[1]};
        }
        __syncthreads();

        if (t < T_STEPS - 1) {
            // -------- Phase D: q_{t+1} = tanh(h @ Wq + bq) -> fp8, sc1 store (supertile) -----
            if (wave < 4) {
                f32x4 acc = {0.f, 0.f, 0.f, 0.f};
#pragma unroll
                for (int kk = 0; kk < 2; ++kk) {
                    short8 a = *(const short8*)(h_lds + l15 * 72 + kk * 32 + quad * 8);
                    acc = MFMA16(a, wQ[kk], acc);
                }
                float q0 = fast_tanh(acc[0] + bqv), q1 = fast_tanh(acc[1] + bqv);
                float q2 = fast_tanh(acc[2] + bqv), q3 = fast_tanh(acc[3] + bqv);
                int pk = __builtin_amdgcn_cvt_pk_fp8_f32(q0, q1, 0, false);
                pk     = __builtin_amdgcn_cvt_pk_fp8_f32(q2, q3, pk, true);
                unsigned char* qdst = qnxt + qdoff;
                asm volatile("global_store_dword %0, %1, off sc0 sc1" :: "v"(qdst), "v"(pk) : "memory");
            }
            // -------- publish FIRST (critical path): drain q stores, bump own step flag ------
            asm volatile("s_waitcnt vmcnt(0)" ::: "memory");
            __syncthreads();
            if (tid == 0)
                __hip_atomic_store(&lflags[bid * 32], t + 1,
                                   __ATOMIC_RELAXED, __HIP_MEMORY_SCOPE_AGENT);
            // -------- off-critical-path tail: gates for t+1, x prefetch for t+2 --------------
            phaseA();
            if (t < T_STEPS - 2) {
                xa = *(const f32x4*)(xlane + (t + 2) * 32);
                xb = *(const f32x4*)(xlane + (t + 2) * 32 + 4);
            }
        }
    }
}

extern "C" void kernel_launch(void* const* d_in, const int* in_sizes, int n_in,
                              void* d_out, int out_size, void* d_ws, size_t ws_size,
                              hipStream_t stream) {
    if (ws_size < WS_NEED) return;
    const float* x      = (const float*)d_in[0];
    const float* adj    = (const float*)d_in[1];
    const float* w_ih   = (const float*)d_in[2];
    const float* w_hh   = (const float*)d_in[3];
    const float* bias   = (const float*)d_in[4];
    const float* w_q    = (const float*)d_in[5];
    const float* bias_q = (const float*)d_in[6];
    float* o = (float*)d_out;
    unsigned char* w = (unsigned char*)d_ws;

    hipFuncSetAttribute((const void*)glstm_kernel,
                        hipFuncAttributeMaxDynamicSharedMemorySize, SMEM_TOT);
    glstm_kernel<<<NBLK, NTHR, SMEM_TOT, stream>>>(x, adj, w_ih, w_hh, bias, w_q, bias_q, o, w);
}